// Round 3
// baseline (461.591 us; speedup 1.0000x reference)
//
#include <hip/hip_runtime.h>
#include <math.h>

#ifndef M_PI
#define M_PI 3.14159265358979323846
#endif

// Shapes: x [64,1024,14,14]; w1 [256,1024]; w2 [256,256,3,3]; w3 [1024,256]
#define NB   64
#define CP   256
#define NCOL 12544

typedef __attribute__((ext_vector_type(8))) short short8;
typedef __attribute__((ext_vector_type(4))) float f32x4;

// ---------------- workspace layout (float offsets) ----------------
static const size_t OF_OUT = 0;            // shared fp32 conv out (3,211,264 f) out1 then out2
static const size_t OF_XC  = 3211264;      // xcode NHWC bf16 region (6,422,528 f worth)
static const size_t OF_Z1P = 3211264;      // z1 padded codes [64][16][16][256] bf16 - reuses XC after conv1
static const size_t OF_Z2C = 5308416;      // z2 codes [64][196][256] bf16
static const size_t OF_WQ1 = 9633792;      // [256][1024] bf16 codes
static const size_t OF_WQ2 = 9764864;      // [256][2304] bf16 codes
static const size_t OF_WQ3 = 10059776;     // [1024][256] bf16 codes
static const size_t OF_R1  = 10190848;
static const size_t OF_R2  = 10191104;
static const size_t OF_R3  = 10191360;
static const size_t OF_T2  = 10192384;     // 256*8 tap aggregates
static const size_t OF_CX  = 10194432;     // 12544 colsum of xcode
static const size_t OF_U2  = 10206976;     // 16384 per-(n,hp,wp) chansum of z1p
static const size_t OF_V2  = 10223360;     // 12544 9-tap sums
static const size_t OF_CZ  = 10235904;     // 12544 colsum z2
static const size_t OF_ST  = 10248448;     // stats (8192 f)

__device__ __forceinline__ unsigned encf(float f) {
    unsigned u = __float_as_uint(f);
    return (u & 0x80000000u) ? ~u : (u | 0x80000000u);
}
__device__ __forceinline__ float decf(unsigned u) {
    return (u & 0x80000000u) ? __uint_as_float(u & 0x7FFFFFFFu) : __uint_as_float(~u);
}
__device__ __forceinline__ float fqv(float v, float mn, float sc) {
    float t = (v - mn) / sc;
    t = fminf(fmaxf(t, 0.0f), 255.0f);
    return rintf(t) * sc + mn;
}
__device__ __forceinline__ float codef(float v, float mn, float sc) {
    float t = (v - mn) / sc;
    t = fminf(fmaxf(t, 0.0f), 255.0f);
    return rintf(t) - 128.0f;
}
__device__ __forceinline__ unsigned short f2bf(float f) { return (unsigned short)(__float_as_uint(f) >> 16); }
__device__ __forceinline__ float bf2f(unsigned short u) { return __uint_as_float(((unsigned)u) << 16); }

__device__ __forceinline__ void glds16(const void* g, void* l) {
    __builtin_amdgcn_global_load_lds((const __attribute__((address_space(1))) unsigned int*)g,
                                     (__attribute__((address_space(3))) unsigned int*)l, 16, 0, 0);
}

// ---------------- small utility kernels ----------------
__global__ __launch_bounds__(64) void k_init(unsigned* su) {
    int t = threadIdx.x;
    if (t < 8) su[t] = (t & 1) ? 0u : 0xFFFFFFFFu;
}

__global__ __launch_bounds__(256) void k_minmax(const float4* __restrict__ p, int n4, unsigned* outu) {
    float mn = INFINITY, mx = -INFINITY;
    int stride = gridDim.x * blockDim.x;
    for (int i = blockIdx.x * blockDim.x + threadIdx.x; i < n4; i += stride) {
        float4 v = p[i];
        mn = fminf(mn, fminf(fminf(v.x, v.y), fminf(v.z, v.w)));
        mx = fmaxf(mx, fmaxf(fmaxf(v.x, v.y), fmaxf(v.z, v.w)));
    }
    for (int o = 32; o; o >>= 1) {
        mn = fminf(mn, __shfl_down(mn, o, 64));
        mx = fmaxf(mx, __shfl_down(mx, o, 64));
    }
    __shared__ float smn[4], smx[4];
    int lane = threadIdx.x & 63, w = threadIdx.x >> 6;
    if (lane == 0) { smn[w] = mn; smx[w] = mx; }
    __syncthreads();
    if (threadIdx.x == 0) {
        for (int i = 1; i < 4; i++) { mn = fminf(mn, smn[i]); mx = fmaxf(mx, smx[i]); }
        atomicMin(&outu[0], encf(mn));
        atomicMax(&outu[1], encf(mx));
    }
}

__global__ __launch_bounds__(64) void k_fqparams(const unsigned* su, float* sf) {
    int t = threadIdx.x;
    if (t < 4) {
        float mn = decf(su[2 * t]), mx = decf(su[2 * t + 1]);
        sf[8 + 3 * t]     = mn;
        sf[8 + 3 * t + 1] = fmaxf((mx - mn) / 255.0f, 1e-8f);
    }
}

// ---------------- weight code kernels ----------------
__global__ __launch_bounds__(256) void k_wcode11(const float* __restrict__ w, const float* __restrict__ pw,
                                                 unsigned short* __restrict__ wc, float* __restrict__ R, int K) {
    int co = blockIdx.x, t = threadIdx.x;
    float mn = pw[0], s = pw[1];
    float sum = 0.f;
    for (int k = t; k < K; k += 256) {
        float c = codef(w[(size_t)co * K + k], mn, s);
        wc[(size_t)co * K + k] = f2bf(c);
        sum += c;
    }
    for (int o = 32; o; o >>= 1) sum += __shfl_down(sum, o, 64);
    __shared__ float sr[4];
    int lane = t & 63, wv = t >> 6;
    if (lane == 0) sr[wv] = sum;
    __syncthreads();
    if (t == 0) R[co] = sr[0] + sr[1] + sr[2] + sr[3];
}

__global__ __launch_bounds__(256) void k_wcode33(const float* __restrict__ w, const float* __restrict__ pw,
                                                 unsigned short* __restrict__ wc, float* __restrict__ R,
                                                 float* __restrict__ T8) {
    int co = blockIdx.x, ci = threadIdx.x;
    float mn = pw[0], s = pw[1];
    float tp[9];
#pragma unroll
    for (int p = 0; p < 9; p++) {
        float c = codef(w[((size_t)co * 256 + ci) * 9 + p], mn, s);
        wc[(size_t)co * 2304 + p * 256 + ci] = f2bf(c);
        tp[p] = c;
    }
    __shared__ float red[4][9];
    __shared__ float sT[9];
    int lane = ci & 63, wv = ci >> 6;
#pragma unroll
    for (int p = 0; p < 9; p++) {
        float v = tp[p];
        for (int o = 32; o; o >>= 1) v += __shfl_down(v, o, 64);
        if (lane == 0) red[wv][p] = v;
    }
    __syncthreads();
    if (ci < 9) sT[ci] = red[0][ci] + red[1][ci] + red[2][ci] + red[3][ci];
    __syncthreads();
    if (ci == 0) {
        float T0 = sT[0], T1 = sT[1], T2 = sT[2], T3 = sT[3], T4 = sT[4],
              T5 = sT[5], T6 = sT[6], T7 = sT[7], T8v = sT[8];
        R[co] = T0 + T1 + T2 + T3 + T4 + T5 + T6 + T7 + T8v;
        float* o = &T8[co * 8];
        o[0] = T0 + T1 + T2;   // top (r=0)
        o[1] = T6 + T7 + T8v;  // bot (r=2)
        o[2] = T0 + T3 + T6;   // left (s=0)
        o[3] = T2 + T5 + T8v;  // right (s=2)
        o[4] = T0; o[5] = T2; o[6] = T6; o[7] = T8v;
    }
}

// ---------------- activation code + transpose to NHWC (+ fused row channel-sum) ----------------
// MODE 0: x fp32 NCHW (C=1024, cq chunks) -> fq codes, dst [n][hw][1024]; rowsum=CX via atomicAdd
// MODE 1: conv-out fp32 NCHW (C=256) -> norm+fq codes, dst padded [n][16][16][256]; rowsum=U2 store
// MODE 2: conv-out fp32 NCHW (C=256) -> norm+fq codes, dst [n][hw][256]; rowsum=CZ store
template <int MODE>
__global__ __launch_bounds__(256) void k_code(const float* __restrict__ src, unsigned short* __restrict__ dst,
                                              const float* __restrict__ mean, const float* __restrict__ sg,
                                              const float* __restrict__ beta, const float* __restrict__ qp,
                                              float* __restrict__ rowsum) {
    __shared__ unsigned short lt[28][264];
    int n = blockIdx.z, hw0 = blockIdx.x * 28, cq = blockIdx.y * 256;
    int t = threadIdx.x;
    const int Csrc = (MODE == 0) ? 1024 : 256;
    float qmn = qp[0], qsc = qp[1];
    const float* sp = src + ((size_t)n * Csrc + cq) * 196 + hw0;
    for (int i = t; i < 7168; i += 256) {
        int c = i / 28, hw = i - c * 28;
        float v = sp[(size_t)c * 196 + hw];
        if (MODE != 0) v = (v - mean[c]) * sg[c] + beta[c];
        lt[hw][c] = f2bf(codef(v, qmn, qsc));
    }
    __syncthreads();
#pragma unroll 4
    for (int i = 0; i < 28; i++) {
        int hw = hw0 + i;
        unsigned short val = lt[i][t];
        size_t da;
        if (MODE == 0) da = ((size_t)n * 196 + hw) * 1024 + cq + t;
        else if (MODE == 1) {
            int h = hw / 14 + 1, w = hw - (hw / 14) * 14 + 1;
            da = (((size_t)n * 16 + h) * 16 + w) * 256 + t;
        } else da = ((size_t)n * 196 + hw) * 256 + t;
        dst[da] = val;
    }
    // fused per-row channel sum (exact: integer-valued codes)
    int lane = t & 63, wv = t >> 6;
    for (int i = wv; i < 28; i += 4) {
        float s = bf2f(lt[i][lane]) + bf2f(lt[i][lane + 64]) +
                  bf2f(lt[i][lane + 128]) + bf2f(lt[i][lane + 192]);
        for (int o = 32; o; o >>= 1) s += __shfl_down(s, o, 64);
        if (lane == 0) {
            int hw = hw0 + i;
            if (MODE == 0) atomicAdd(&rowsum[n * 196 + hw], s);
            else if (MODE == 1) {
                int h = hw / 14 + 1, w = hw - (hw / 14) * 14 + 1;
                rowsum[((size_t)n * 16 + h) * 16 + w] = s;
            } else rowsum[n * 196 + hw] = s;
        }
    }
}

// V2[j] = 9-tap sum of U2 (padded [n][16][16])
__global__ __launch_bounds__(256) void k_v2(const float* __restrict__ U, float* __restrict__ V) {
    int j = blockIdx.x * 256 + threadIdx.x;
    if (j >= NCOL) return;
    int n = j / 196, hw = j - n * 196, h = hw / 14, w = hw - (hw / 14) * 14;
    const float* u = U + (size_t)n * 256;
    float s = 0.f;
#pragma unroll
    for (int r = 0; r < 3; r++)
#pragma unroll
        for (int c = 0; c < 3; c++) s += u[(h + r) * 16 + (w + c)];
    V[j] = s;
}

// ---------------- MFMA implicit-GEMM conv, BK=64, XOR-swizzled LDS, optional K-split ----------------
// MI=2 -> BM=64 ; MI=4 -> BM=128. BN=128.
// MODE 0: B = [12544][K] codes. MODE 1: B = z1p padded codes, K=2304 (k = p*256+ci).
// KS>1: grid.z = K-split; partial results accumulated with atomicAdd (out must be pre-zeroed);
//       affine correction terms added only by split 0.
template <int MI, int MODE, int KS>
__global__ __launch_bounds__(256) void k_convmm(const unsigned short* __restrict__ A,
                                                const unsigned short* __restrict__ B,
                                                const float* __restrict__ R, const float* __restrict__ T8,
                                                const float* __restrict__ Cj,
                                                const float* __restrict__ pw, const float* __restrict__ pz,
                                                float* __restrict__ out, int Cout, int K) {
    constexpr int BM = MI * 32;
    __shared__ __align__(16) unsigned short As[BM * 64];
    __shared__ __align__(16) unsigned short Bs[128 * 64];
    int tid = threadIdx.x;
    int lane = tid & 63, wave = tid >> 6;
    int wm = wave >> 1, wn = wave & 1;
    int row0 = blockIdx.y * BM, jb = blockIdx.x * 128;
    int ksplit = (KS > 1) ? blockIdx.z : 0;
    int Kper = K / KS, kbeg = ksplit * Kper;
    int nk = Kper >> 6;

    // staging: thread covers 16B (8 codes); row within 32-row issue group, swizzled chunk
    int sr = tid >> 3, spos = tid & 7;
    int sc = spos ^ (sr & 7);        // global k-chunk this thread fetches

    const unsigned short* gA[4];
#pragma unroll
    for (int q = 0; q < BM / 32; q++)
        gA[q] = A + (size_t)(row0 + q * 32 + sr) * K + kbeg + sc * 8;

    size_t cb[4];
#pragma unroll
    for (int q = 0; q < 4; q++) {
        int j = jb + q * 32 + sr;
        if (MODE == 0) cb[q] = (size_t)j * K + kbeg + sc * 8;
        else {
            int n = j / 196, hw = j - n * 196, h = hw / 14, w = hw - (hw / 14) * 14;
            cb[q] = (((size_t)n * 16 + h) * 16 + w) * 256 + sc * 8;   // tap/kin added per k-step
        }
    }

    f32x4 acc[MI][4];
#pragma unroll
    for (int mi = 0; mi < MI; mi++)
#pragma unroll
        for (int ni = 0; ni < 4; ni++) acc[mi][ni] = 0.f;

    // fragment-read swizzle constants
    int mr = lane & 15, kq = lane >> 4, lx = lane & 7;
    int c0 = ((kq) ^ lx) * 8, c1 = ((4 + kq) ^ lx) * 8;

    for (int ks = 0; ks < nk; ks++) {
        __syncthreads();
#pragma unroll
        for (int q = 0; q < BM / 32; q++)
            glds16(gA[q] + ks * 64, &As[(q * 32 + sr) * 64 + spos * 8]);
        if (MODE == 0) {
#pragma unroll
            for (int q = 0; q < 4; q++)
                glds16(B + cb[q] + ks * 64, &Bs[(q * 32 + sr) * 64 + spos * 8]);
        } else {
            int k = kbeg + ks * 64;
            int p = k >> 8, kin = k & 255;
            int rr = p / 3, ss = p - rr * 3;
            size_t add = (size_t)(rr * 16 + ss) * 256 + kin;
#pragma unroll
            for (int q = 0; q < 4; q++)
                glds16(B + cb[q] + add, &Bs[(q * 32 + sr) * 64 + spos * 8]);
        }
        __syncthreads();

        short8 af[MI][2], bv[4][2];
#pragma unroll
        for (int mi = 0; mi < MI; mi++) {
            int m = wm * (MI * 16) + mi * 16 + mr;
            af[mi][0] = *(const short8*)&As[m * 64 + c0];
            af[mi][1] = *(const short8*)&As[m * 64 + c1];
        }
#pragma unroll
        for (int ni = 0; ni < 4; ni++) {
            int nn = wn * 64 + ni * 16 + mr;
            bv[ni][0] = *(const short8*)&Bs[nn * 64 + c0];
            bv[ni][1] = *(const short8*)&Bs[nn * 64 + c1];
        }
#pragma unroll
        for (int h = 0; h < 2; h++)
#pragma unroll
            for (int mi = 0; mi < MI; mi++)
#pragma unroll
                for (int ni = 0; ni < 4; ni++)
                    acc[mi][ni] = __builtin_amdgcn_mfma_f32_16x16x32_bf16(af[mi][h], bv[ni][h], acc[mi][ni], 0, 0, 0);
    }

    // epilogue: value = aw*az*S + [split0 only:] aw*bz*(R - PT) + bw*az*Cj + bw*bz*Kvalid
    float aw = pw[1], bw = pw[0] + 128.f * pw[1];
    float az = pz[1], bz = pz[0] + 128.f * pz[1];
    float caa = aw * az, cR = aw * bz, cC = bw * az, cK = bw * bz;
    int colbase = jb + wn * 64 + (lane & 15);
    int rowq = (lane >> 4) * 4;
#pragma unroll
    for (int ni = 0; ni < 4; ni++) {
        int j = colbase + ni * 16;
        int nimg = j / 196, hw = j - nimg * 196;
        float cj = Cj[j];
        float constterm;
        float pt = 0.f, pb = 0.f, pl = 0.f, pr = 0.f, ctl = 0.f, ctr = 0.f, cbl = 0.f, cbr = 0.f;
        if (MODE == 1) {
            int h = hw / 14, w = hw - (hw / 14) * 14;
            pt = (h == 0) ? 1.f : 0.f;  pb = (h == 13) ? 1.f : 0.f;
            pl = (w == 0) ? 1.f : 0.f;  pr = (w == 13) ? 1.f : 0.f;
            ctl = pt * pl; ctr = pt * pr; cbl = pb * pl; cbr = pb * pr;
            float miss = 3.f * (pt + pb + pl + pr) - (ctl + ctr + cbl + cbr);
            constterm = cK * (256.f * (9.f - miss));
        } else {
            constterm = cK * (float)K;
        }
#pragma unroll
        for (int mi = 0; mi < MI; mi++) {
            int co0 = row0 + wm * (MI * 16) + mi * 16 + rowq;
#pragma unroll
            for (int l = 0; l < 4; l++) {
                int co = co0 + l;
                float rsum = R[co];
                if (MODE == 1) {
                    const float* t8 = &T8[co * 8];
                    rsum -= pt * t8[0] + pb * t8[1] + pl * t8[2] + pr * t8[3]
                          - ctl * t8[4] - ctr * t8[5] - cbl * t8[6] - cbr * t8[7];
                }
                float corr = (KS == 1 || ksplit == 0) ? (cR * rsum + cC * cj + constterm) : 0.f;
                float v = caa * acc[mi][ni][l] + corr;
                size_t idx = ((size_t)nimg * Cout + co) * 196 + hw;
                if (KS > 1) atomicAdd(&out[idx], v);
                else out[idx] = v;
            }
        }
    }
}

// ---------------- per-channel stats / finalize ----------------
__global__ __launch_bounds__(256) void k_chstats(const float* __restrict__ buf, int C,
                                                 float* sum_o, float* mn_o, float* mx_o) {
    int c = blockIdx.x, tid = threadIdx.x;
    float sm = 0.f, mn = INFINITY, mx = -INFINITY;
    for (int n = 0; n < NB; n++) {
        const float* p = buf + (size_t)n * C * 196 + (size_t)c * 196;
        for (int hwp = tid; hwp < 196; hwp += 256) {
            float v = p[hwp];
            sm += v; mn = fminf(mn, v); mx = fmaxf(mx, v);
        }
    }
    for (int o = 32; o; o >>= 1) {
        sm += __shfl_down(sm, o, 64);
        mn = fminf(mn, __shfl_down(mn, o, 64));
        mx = fmaxf(mx, __shfl_down(mx, o, 64));
    }
    __shared__ float s1[4], s2[4], s3[4];
    int lane = tid & 63, w = tid >> 6;
    if (lane == 0) { s1[w] = sm; s2[w] = mn; s3[w] = mx; }
    __syncthreads();
    if (tid == 0) {
        for (int i = 1; i < 4; i++) { sm += s1[i]; mn = fminf(mn, s2[i]); mx = fmaxf(mx, s3[i]); }
        sum_o[c] = sm; mn_o[c] = mn; mx_o[c] = mx;
    }
}

__global__ __launch_bounds__(256) void k_finnorm(int C, const float* __restrict__ gamma, const float* __restrict__ beta,
                                                 const float* __restrict__ sum_i, const float* __restrict__ mn_i,
                                                 const float* __restrict__ mx_i, float* mean_o, float* sg_o,
                                                 float* qp, float scale_fix) {
    int tid = threadIdx.x;
    int lane = tid & 63, w = tid >> 6;
    __shared__ float sa[4], sb[4];
    float gmn = INFINITY, gmx = -INFINITY;
    for (int c = tid; c < C; c += 256) { float g = gamma[c]; gmn = fminf(gmn, g); gmx = fmaxf(gmx, g); }
    for (int o = 32; o; o >>= 1) { gmn = fminf(gmn, __shfl_down(gmn, o, 64)); gmx = fmaxf(gmx, __shfl_down(gmx, o, 64)); }
    if (lane == 0) { sa[w] = gmn; sb[w] = gmx; }
    __syncthreads();
    gmn = fminf(fminf(sa[0], sa[1]), fminf(sa[2], sa[3]));
    gmx = fmaxf(fmaxf(sb[0], sb[1]), fmaxf(sb[2], sb[3]));
    float gsc = fmaxf((gmx - gmn) / 255.0f, 1e-8f);
    __syncthreads();
    float qmn = INFINITY, qmx = -INFINITY;
    for (int c = tid; c < C; c += 256) {
        float mean = sum_i[c] / 12544.0f;
        float rng  = mx_i[c] - mn_i[c];
        float qg   = fqv(gamma[c], gmn, gsc);
        float s    = qg / (rng * scale_fix + 1e-5f);
        mean_o[c] = mean; sg_o[c] = s;
        float b  = beta[c];
        float lo = (mn_i[c] - mean) * s + b;
        float hi = (mx_i[c] - mean) * s + b;
        qmn = fminf(qmn, fminf(lo, hi));
        qmx = fmaxf(qmx, fmaxf(lo, hi));
    }
    for (int o = 32; o; o >>= 1) { qmn = fminf(qmn, __shfl_down(qmn, o, 64)); qmx = fmaxf(qmx, __shfl_down(qmx, o, 64)); }
    if (lane == 0) { sa[w] = qmn; sb[w] = qmx; }
    __syncthreads();
    if (tid == 0) {
        qmn = fminf(fminf(sa[0], sa[1]), fminf(sa[2], sa[3]));
        qmx = fmaxf(fmaxf(sb[0], sb[1]), fmaxf(sb[2], sb[3]));
        qp[0] = qmn;
        qp[1] = fmaxf((qmx - qmn) / 255.0f, 1e-8f);
    }
}

__global__ __launch_bounds__(256) void k_final(const float* __restrict__ x, float* __restrict__ out,
                                               const float* __restrict__ mean, const float* __restrict__ sg,
                                               const float* __restrict__ beta, const float* __restrict__ sf,
                                               const float* __restrict__ qp) {
    float xmn = sf[8], xsc = sf[9];
    float qmn = qp[0], qsc = qp[1];
    const float4* xp = (const float4*)x;
    float4* yp = (float4*)out;
    int n4 = 12845056 / 4;
    int i = blockIdx.x * blockDim.x + threadIdx.x;
    int str = gridDim.x * blockDim.x;
    for (; i < n4; i += str) {
        int e = i * 4;
        int c = (e / 196) & 1023;
        float m = mean[c], s = sg[c], b = beta[c];
        float4 xv = xp[i], ov = yp[i], r;
        r.x = fqv(xv.x, xmn, xsc) + fqv((ov.x - m) * s + b, qmn, qsc);
        r.y = fqv(xv.y, xmn, xsc) + fqv((ov.y - m) * s + b, qmn, qsc);
        r.z = fqv(xv.z, xmn, xsc) + fqv((ov.z - m) * s + b, qmn, qsc);
        r.w = fqv(xv.w, xmn, xsc) + fqv((ov.w - m) * s + b, qmn, qsc);
        yp[i] = r;
    }
}

extern "C" void kernel_launch(void* const* d_in, const int* in_sizes, int n_in,
                              void* d_out, int out_size, void* d_ws, size_t ws_size,
                              hipStream_t stream) {
    const float* x  = (const float*)d_in[0];
    const float* w1 = (const float*)d_in[1];
    const float* g1 = (const float*)d_in[2];
    const float* b1 = (const float*)d_in[3];
    const float* w2 = (const float*)d_in[4];
    const float* g2 = (const float*)d_in[5];
    const float* b2 = (const float*)d_in[6];
    const float* w3 = (const float*)d_in[7];
    const float* g3 = (const float*)d_in[8];
    const float* b3 = (const float*)d_in[9];
    float* out = (float*)d_out;

    float* W = (float*)d_ws;
    float* OUT = W + OF_OUT;
    unsigned short* xc   = (unsigned short*)(W + OF_XC);
    unsigned short* z1p  = (unsigned short*)(W + OF_Z1P);
    unsigned short* z2c  = (unsigned short*)(W + OF_Z2C);
    unsigned short* wq1c = (unsigned short*)(W + OF_WQ1);
    unsigned short* wq2c = (unsigned short*)(W + OF_WQ2);
    unsigned short* wq3c = (unsigned short*)(W + OF_WQ3);
    float* R1 = W + OF_R1;  float* R2 = W + OF_R2;  float* R3 = W + OF_R3;
    float* T2 = W + OF_T2;
    float* CX = W + OF_CX;  float* U2 = W + OF_U2;  float* V2 = W + OF_V2;  float* CZ = W + OF_CZ;
    float* S = W + OF_ST;
    unsigned* Su = (unsigned*)S;

    const float scale_fix =
        (float)((0.5 * 0.35) * (1.0 + sqrt(M_PI * log(4.0))) / sqrt(2.0 * log(12544.0)));

    // fq params for x, w1, w2, w3
    k_init<<<1, 64, 0, stream>>>(Su);
    k_minmax<<<1024, 256, 0, stream>>>((const float4*)x,  12845056 / 4, Su + 0);
    k_minmax<<<64,   256, 0, stream>>>((const float4*)w1, 262144 / 4,  Su + 2);
    k_minmax<<<128,  256, 0, stream>>>((const float4*)w2, 589824 / 4,  Su + 4);
    k_minmax<<<64,   256, 0, stream>>>((const float4*)w3, 262144 / 4,  Su + 6);
    k_fqparams<<<1, 64, 0, stream>>>(Su, S);

    // weight codes + reductions
    k_wcode11<<<256,  256, 0, stream>>>(w1, S + 11, wq1c, R1, 1024);
    k_wcode11<<<1024, 256, 0, stream>>>(w3, S + 17, wq3c, R3, 256);
    k_wcode33<<<256,  256, 0, stream>>>(w2, S + 14, wq2c, R2, T2);

    // x -> NHWC codes (+ fused colsum via atomics)
    hipMemsetAsync(CX, 0, 12544 * 4, stream);
    k_code<0><<<dim3(7, 4, 64), 256, 0, stream>>>(x, xc, S, S, S, S + 8, CX);

    // conv1 (K-split x2, atomic accumulate) -> OUT
    hipMemsetAsync(OUT, 0, (size_t)3211264 * 4, stream);
    k_convmm<2, 0, 2><<<dim3(98, 4, 2), 256, 0, stream>>>(wq1c, xc, R1, nullptr, CX, S + 11, S + 8, OUT, 256, 1024);

    // range_norm1 -> z1 padded codes (+ fused U2 row-sums)
    k_chstats<<<256, 256, 0, stream>>>(OUT, 256, S + 1088, S + 576, S + 832);
    k_finnorm<<<1, 256, 0, stream>>>(256, g1, b1, S + 1088, S + 576, S + 832, S + 64, S + 320, S + 20, scale_fix);
    hipMemsetAsync(z1p, 0, (size_t)64 * 16 * 16 * 256 * 2, stream);
    hipMemsetAsync(U2, 0, 16384 * 4, stream);
    k_code<1><<<dim3(7, 1, 64), 256, 0, stream>>>(OUT, z1p, S + 64, S + 320, b1, S + 20, U2);
    k_v2<<<49, 256, 0, stream>>>(U2, V2);

    // conv2 (K-split x2, atomic accumulate) -> OUT
    hipMemsetAsync(OUT, 0, (size_t)3211264 * 4, stream);
    k_convmm<2, 1, 2><<<dim3(98, 4, 2), 256, 0, stream>>>(wq2c, z1p, R2, T2, V2, S + 14, S + 20, OUT, 256, 2304);

    // range_norm2 -> z2 codes (+ fused CZ row-sums)
    k_chstats<<<256, 256, 0, stream>>>(OUT, 256, S + 2368, S + 1856, S + 2112);
    k_finnorm<<<1, 256, 0, stream>>>(256, g2, b2, S + 2368, S + 1856, S + 2112, S + 1344, S + 1600, S + 23, scale_fix);
    k_code<2><<<dim3(7, 1, 64), 256, 0, stream>>>(OUT, z2c, S + 1344, S + 1600, b2, S + 23, CZ);

    // conv3 -> d_out (direct store)
    k_convmm<4, 0, 1><<<dim3(98, 8), 256, 0, stream>>>(wq3c, z2c, R3, nullptr, CZ, S + 17, S + 23, out, 1024, 256);

    // range_norm3 stats + final fused residual add (in place in d_out)
    k_chstats<<<1024, 256, 0, stream>>>(out, 1024, S + 6720, S + 4672, S + 5696);
    k_finnorm<<<1, 256, 0, stream>>>(1024, g3, b3, S + 6720, S + 4672, S + 5696, S + 2624, S + 3648, S + 26, scale_fix);
    k_final<<<2048, 256, 0, stream>>>(x, out, S + 2624, S + 3648, b3, S, S + 26);
}

// Round 4
// 382.952 us; speedup vs baseline: 1.2053x; 1.2053x over previous
//
#include <hip/hip_runtime.h>
#include <math.h>

#ifndef M_PI
#define M_PI 3.14159265358979323846
#endif

// Shapes: x [64,1024,14,14]; w1 [256,1024]; w2 [256,256,3,3]; w3 [1024,256]
#define NB   64
#define NCOL 12544

typedef __attribute__((ext_vector_type(4))) int int4v;

// ---------------- workspace layout (float offsets) ----------------
static const size_t OF_OUT = 0;            // conv1/conv2 fp32 NHWC out [12544][256]
static const size_t OF_XC  = 3211264;      // x codes i8 NHWC [64][196][1024]
static const size_t OF_Z1P = 6422528;      // z1 codes i8 padded [64][16][16][256]
static const size_t OF_Z2C = 7471104;      // z2 codes i8 [12544][256]
static const size_t OF_WQ1 = 8273920;      // w1 codes i8 [256][1024]
static const size_t OF_WQ2 = 8339456;      // w2 codes i8 [256][9*256]
static const size_t OF_WQ3 = 8486912;      // w3 codes i8 [1024][256]
static const size_t OF_R1  = 8552448;
static const size_t OF_R2  = 8552704;
static const size_t OF_R3  = 8552960;
static const size_t OF_T2  = 8553984;      // 256*8 tap aggregates
static const size_t OF_CX  = 8556032;      // 12544
static const size_t OF_U2  = 8568576;      // 16384
static const size_t OF_V2  = 8584960;      // 12544
static const size_t OF_CZ  = 8597504;      // 12544
static const size_t OF_AS  = 8610048;      // stats atomics: sums[1536] @0, mxenc[1536] @1536, mnenc[1536] @3072
static const size_t OF_ST  = 8614656;      // 64 misc floats
static const size_t OF_MS  = 8614720;      // mean/sg: m1@0 sg1@256 m2@512 sg2@768 m3@1024 sg3@2048

__device__ __forceinline__ unsigned encf(float f) {
    unsigned u = __float_as_uint(f);
    return (u & 0x80000000u) ? ~u : (u | 0x80000000u);
}
__device__ __forceinline__ float decf(unsigned u) {
    return (u & 0x80000000u) ? __uint_as_float(u & 0x7FFFFFFFu) : __uint_as_float(~u);
}
__device__ __forceinline__ float fqv(float v, float mn, float sc) {
    float t = (v - mn) / sc;
    t = fminf(fmaxf(t, 0.0f), 255.0f);
    return rintf(t) * sc + mn;
}
// centered code (integer-valued in [-128,127])
__device__ __forceinline__ float codef(float v, float mn, float sc) {
    float t = (v - mn) / sc;
    t = fminf(fmaxf(t, 0.0f), 255.0f);
    return rintf(t) - 128.0f;
}
__device__ __forceinline__ unsigned short f2bf(float f) { return (unsigned short)(__float_as_uint(f) >> 16); }
__device__ __forceinline__ float bf2f(unsigned short u) { return __uint_as_float(((unsigned)u) << 16); }
__device__ __forceinline__ int pack4(float a, float b, float c, float d) {
    return (int)(unsigned char)(signed char)(int)a | ((int)(unsigned char)(signed char)(int)b << 8) |
           ((int)(unsigned char)(signed char)(int)c << 16) | ((int)(unsigned char)(signed char)(int)d << 24);
}
__device__ __forceinline__ void glds16(const void* g, void* l) {
    __builtin_amdgcn_global_load_lds((const __attribute__((address_space(1))) unsigned int*)g,
                                     (__attribute__((address_space(3))) unsigned int*)l, 16, 0, 0);
}

// ---------------- small utility kernels ----------------
__global__ __launch_bounds__(64) void k_init(unsigned* su) {
    int t = threadIdx.x;
    if (t < 8) su[t] = (t & 1) ? 0u : 0xFFFFFFFFu;
}

__global__ __launch_bounds__(256) void k_minmax(const float4* __restrict__ p, int n4, unsigned* outu) {
    float mn = INFINITY, mx = -INFINITY;
    int stride = gridDim.x * blockDim.x;
    for (int i = blockIdx.x * blockDim.x + threadIdx.x; i < n4; i += stride) {
        float4 v = p[i];
        mn = fminf(mn, fminf(fminf(v.x, v.y), fminf(v.z, v.w)));
        mx = fmaxf(mx, fmaxf(fmaxf(v.x, v.y), fmaxf(v.z, v.w)));
    }
    for (int o = 32; o; o >>= 1) {
        mn = fminf(mn, __shfl_down(mn, o, 64));
        mx = fmaxf(mx, __shfl_down(mx, o, 64));
    }
    __shared__ float smn[4], smx[4];
    int lane = threadIdx.x & 63, w = threadIdx.x >> 6;
    if (lane == 0) { smn[w] = mn; smx[w] = mx; }
    __syncthreads();
    if (threadIdx.x == 0) {
        for (int i = 1; i < 4; i++) { mn = fminf(mn, smn[i]); mx = fmaxf(mx, smx[i]); }
        atomicMin(&outu[0], encf(mn));
        atomicMax(&outu[1], encf(mx));
    }
}

__global__ __launch_bounds__(64) void k_fqparams(const unsigned* su, float* sf) {
    int t = threadIdx.x;
    if (t < 4) {
        float mn = decf(su[2 * t]), mx = decf(su[2 * t + 1]);
        sf[8 + 3 * t]     = mn;
        sf[8 + 3 * t + 1] = fmaxf((mx - mn) / 255.0f, 1e-8f);
    }
}

// ---------------- weight code kernels (i8) ----------------
__global__ __launch_bounds__(256) void k_wcode11(const float* __restrict__ w, const float* __restrict__ pw,
                                                 signed char* __restrict__ wc, float* __restrict__ R, int K) {
    int co = blockIdx.x, t = threadIdx.x;
    float mn = pw[0], s = pw[1];
    float sum = 0.f;
    for (int k0 = t * 4; k0 < K; k0 += 1024) {
        float4 v = *(const float4*)&w[(size_t)co * K + k0];
        float c0 = codef(v.x, mn, s), c1 = codef(v.y, mn, s), c2 = codef(v.z, mn, s), c3 = codef(v.w, mn, s);
        *(int*)&wc[(size_t)co * K + k0] = pack4(c0, c1, c2, c3);
        sum += c0 + c1 + c2 + c3;
    }
    for (int o = 32; o; o >>= 1) sum += __shfl_down(sum, o, 64);
    __shared__ float sr_[4];
    int lane = t & 63, wv = t >> 6;
    if (lane == 0) sr_[wv] = sum;
    __syncthreads();
    if (t == 0) R[co] = sr_[0] + sr_[1] + sr_[2] + sr_[3];
}

__global__ __launch_bounds__(256) void k_wcode33(const float* __restrict__ w, const float* __restrict__ pw,
                                                 signed char* __restrict__ wc, float* __restrict__ R,
                                                 float* __restrict__ T8) {
    int co = blockIdx.x, ci = threadIdx.x;
    float mn = pw[0], s = pw[1];
    float tp[9];
#pragma unroll
    for (int p = 0; p < 9; p++) {
        float c = codef(w[((size_t)co * 256 + ci) * 9 + p], mn, s);
        wc[(size_t)co * 2304 + p * 256 + ci] = (signed char)(int)c;
        tp[p] = c;
    }
    __shared__ float red[4][9];
    __shared__ float sT[9];
    int lane = ci & 63, wv = ci >> 6;
#pragma unroll
    for (int p = 0; p < 9; p++) {
        float v = tp[p];
        for (int o = 32; o; o >>= 1) v += __shfl_down(v, o, 64);
        if (lane == 0) red[wv][p] = v;
    }
    __syncthreads();
    if (ci < 9) sT[ci] = red[0][ci] + red[1][ci] + red[2][ci] + red[3][ci];
    __syncthreads();
    if (ci == 0) {
        float T0 = sT[0], T1 = sT[1], T2 = sT[2], T3 = sT[3],
              T5 = sT[5], T6 = sT[6], T7 = sT[7], T8v = sT[8];
        R[co] = T0 + T1 + T2 + T3 + sT[4] + T5 + T6 + T7 + T8v;
        float* o = &T8[co * 8];
        o[0] = T0 + T1 + T2;   // top
        o[1] = T6 + T7 + T8v;  // bot
        o[2] = T0 + T3 + T6;   // left
        o[3] = T2 + T5 + T8v;  // right
        o[4] = T0; o[5] = T2; o[6] = T6; o[7] = T8v;
    }
}

// ---------------- x NCHW fp32 -> NHWC i8 codes + CX rowsum ----------------
__global__ __launch_bounds__(256) void k_code0(const float* __restrict__ x, signed char* __restrict__ dst,
                                               const float* __restrict__ qp, float* __restrict__ CX) {
    __shared__ unsigned short lt[28][264];
    int n = blockIdx.z, hw0 = blockIdx.x * 28, cq = blockIdx.y * 256;
    int t = threadIdx.x;
    float qmn = qp[0], qsc = qp[1];
    const float* sp = x + ((size_t)n * 1024 + cq) * 196 + hw0;
    for (int i = t; i < 7168; i += 256) {
        int c = i / 28, hw = i - c * 28;
        lt[hw][c] = f2bf(codef(sp[(size_t)c * 196 + hw], qmn, qsc));
    }
    __syncthreads();
    int lane = t & 63, wv = t >> 6;
    int c0 = lane * 4;
#pragma unroll
    for (int s = 0; s < 7; s++) {
        int i = s * 4 + wv;
        int pk = pack4(bf2f(lt[i][c0]), bf2f(lt[i][c0 + 1]), bf2f(lt[i][c0 + 2]), bf2f(lt[i][c0 + 3]));
        *(int*)&dst[((size_t)n * 196 + hw0 + i) * 1024 + cq + c0] = pk;
    }
    for (int i = wv; i < 28; i += 4) {
        float s = bf2f(lt[i][lane]) + bf2f(lt[i][lane + 64]) +
                  bf2f(lt[i][lane + 128]) + bf2f(lt[i][lane + 192]);
        for (int o = 32; o; o >>= 1) s += __shfl_down(s, o, 64);
        if (lane == 0) atomicAdd(&CX[n * 196 + hw0 + i], s);
    }
}

// ---------------- NHWC elementwise norm+quant -> i8 codes + rowsum ----------------
// PAD=1: dst = z1p padded [n][16][16][256], rowsum = U2 (padded). PAD=0: dst=[j][256], rowsum=CZ.
template <int PAD>
__global__ __launch_bounds__(256) void k_codeE(const float* __restrict__ src, signed char* __restrict__ dst,
                                               const float* __restrict__ mean, const float* __restrict__ sg,
                                               const float* __restrict__ beta, const float* __restrict__ qp,
                                               float* __restrict__ rowsum) {
    int t = threadIdx.x, lane = t & 63, wv = t >> 6;
    int c4 = lane * 4;
    float4 m4 = *(const float4*)&mean[c4];
    float4 s4 = *(const float4*)&sg[c4];
    float4 b4 = *(const float4*)&beta[c4];
    float qmn = qp[0], qsc = qp[1];
#pragma unroll
    for (int r = 0; r < 4; r++) {
        int j = blockIdx.x * 16 + wv * 4 + r;
        float4 v = *(const float4*)&src[(size_t)j * 256 + c4];
        float c0 = codef((v.x - m4.x) * s4.x + b4.x, qmn, qsc);
        float c1 = codef((v.y - m4.y) * s4.y + b4.y, qmn, qsc);
        float c2 = codef((v.z - m4.z) * s4.z + b4.z, qmn, qsc);
        float c3 = codef((v.w - m4.w) * s4.w + b4.w, qmn, qsc);
        int n = j / 196, hw = j - n * 196, h = hw / 14, w = hw - (hw / 14) * 14;
        size_t di;
        if (PAD) di = (((size_t)n * 16 + h + 1) * 16 + (w + 1)) * 256 + c4;
        else     di = (size_t)j * 256 + c4;
        *(int*)&dst[di] = pack4(c0, c1, c2, c3);
        float s = c0 + c1 + c2 + c3;
        for (int o = 32; o; o >>= 1) s += __shfl_down(s, o, 64);
        if (lane == 0) {
            if (PAD) rowsum[((size_t)n * 16 + h + 1) * 16 + (w + 1)] = s;
            else     rowsum[j] = s;
        }
    }
}

// V2[j] = 9-tap sum of U2 (padded [n][16][16])
__global__ __launch_bounds__(256) void k_v2(const float* __restrict__ U, float* __restrict__ V) {
    int j = blockIdx.x * 256 + threadIdx.x;
    if (j >= NCOL) return;
    int n = j / 196, hw = j - n * 196, h = hw / 14, w = hw - (hw / 14) * 14;
    const float* u = U + (size_t)n * 256;
    float s = 0.f;
#pragma unroll
    for (int r = 0; r < 3; r++)
#pragma unroll
        for (int c = 0; c < 3; c++) s += u[(h + r) * 16 + (w + c)];
    V[j] = s;
}

// ---------------- conv1/conv2: i8 MFMA, A=acts (M=128 img), B=weights (N=64 co), BK=128, dbuf ----------------
// MODE 0: Acts = [j][K] codes (conv1, K=1024). MODE 1: Acts = z1p padded, K=2304 (k = p*256+ci).
// Output NHWC fp32 + fused per-channel stats atomics.
template <int MODE>
__global__ __launch_bounds__(256, 2) void k_conv12(const signed char* __restrict__ Acts,
                                                   const signed char* __restrict__ Wts,
                                                   const float* __restrict__ R, const float* __restrict__ T8,
                                                   const float* __restrict__ Cj,
                                                   const float* __restrict__ pw, const float* __restrict__ pz,
                                                   float* __restrict__ outNHWC, int K,
                                                   float* __restrict__ s_sum, unsigned* __restrict__ s_mn,
                                                   unsigned* __restrict__ s_mx) {
    __shared__ __align__(16) signed char As[2 * 16384];   // 2 x 128 rows x 128B
    __shared__ __align__(16) signed char Bs[2 * 8192];    // 2 x 64 rows x 128B
    int tid = threadIdx.x, lane = tid & 63, wave = tid >> 6;
    int wm = wave >> 1, wn = wave & 1;
    int jb = blockIdx.x * 128, cob = blockIdx.y * 64;
    int sr = tid >> 3, spos = tid & 7, sc = spos ^ (sr & 7);

    const signed char* aq[4];
#pragma unroll
    for (int q = 0; q < 4; q++) {
        int j = jb + q * 32 + sr;
        if (MODE == 0) aq[q] = Acts + (size_t)j * K + sc * 16;
        else {
            int n = j / 196, hw = j - n * 196, h = hw / 14, w = hw - (hw / 14) * 14;
            aq[q] = Acts + (((size_t)n * 16 + h) * 16 + w) * 256 + sc * 16;
        }
    }
    const signed char* bq[2];
#pragma unroll
    for (int q = 0; q < 2; q++) bq[q] = Wts + (size_t)(cob + q * 32 + sr) * K + sc * 16;

    int4v acc[4][2];
#pragma unroll
    for (int mi = 0; mi < 4; mi++)
#pragma unroll
        for (int ni = 0; ni < 2; ni++) acc[mi][ni] = (int4v)0;

    int nk = K >> 7;
    auto stage = [&](int b, int ks) {
        size_t koA;
        if (MODE == 0) koA = (size_t)ks << 7;
        else {
            int k = ks << 7;
            int p = k >> 8, kin = k & 255;
            int rr = p / 3, ss = p - 3 * rr;
            koA = (size_t)(rr * 16 + ss) * 256 + kin;
        }
#pragma unroll
        for (int q = 0; q < 4; q++)
            glds16(aq[q] + koA, &As[b * 16384 + (q * 32 + sr) * 128 + spos * 16]);
#pragma unroll
        for (int q = 0; q < 2; q++)
            glds16(bq[q] + ((size_t)ks << 7), &Bs[b * 8192 + (q * 32 + sr) * 128 + spos * 16]);
    };

    int l15 = lane & 15, kq = lane >> 4, sw = l15 & 7;
    stage(0, 0);
    for (int ks = 0; ks < nk; ks++) {
        __syncthreads();
        if (ks + 1 < nk) stage((ks + 1) & 1, ks + 1);
        int b = ks & 1;
#pragma unroll
        for (int kc = 0; kc < 2; kc++) {
            int col = ((kc * 4 + kq) ^ sw) << 4;
            int4v a[4], bb[2];
#pragma unroll
            for (int mi = 0; mi < 4; mi++)
                a[mi] = *(const int4v*)&As[b * 16384 + (wm * 64 + mi * 16 + l15) * 128 + col];
#pragma unroll
            for (int ni = 0; ni < 2; ni++)
                bb[ni] = *(const int4v*)&Bs[b * 8192 + (wn * 32 + ni * 16 + l15) * 128 + col];
#pragma unroll
            for (int mi = 0; mi < 4; mi++)
#pragma unroll
                for (int ni = 0; ni < 2; ni++)
                    acc[mi][ni] = __builtin_amdgcn_mfma_i32_16x16x64_i8(a[mi], bb[ni], acc[mi][ni], 0, 0, 0);
        }
    }

    // epilogue: value = aw*az*S + aw*bz*(R-PT) + bw*az*Cj + bw*bz*Kvalid ; NHWC store + fused stats
    float aw = pw[1], bw = pw[0] + 128.f * pw[1];
    float az = pz[1], bz = pz[0] + 128.f * pz[1];
    float caa = aw * az, cR = aw * bz, cC = bw * az, cK = bw * bz;
    int cco[2]; float rr0[2]; float t8v[2][8];
#pragma unroll
    for (int ni = 0; ni < 2; ni++) {
        cco[ni] = cob + wn * 32 + ni * 16 + l15;
        rr0[ni] = R[cco[ni]];
        if (MODE == 1) {
#pragma unroll
            for (int p = 0; p < 8; p++) t8v[ni][p] = T8[cco[ni] * 8 + p];
        }
    }
    float ssm[2] = {0.f, 0.f}, smnv[2] = {INFINITY, INFINITY}, smxv[2] = {-INFINITY, -INFINITY};
#pragma unroll
    for (int mi = 0; mi < 4; mi++)
#pragma unroll
        for (int reg = 0; reg < 4; reg++) {
            int j = jb + wm * 64 + mi * 16 + kq * 4 + reg;
            int n = j / 196, hw = j - n * 196;
            float cj = Cj[j];
            float constterm;
            float pt = 0.f, pb = 0.f, pl = 0.f, pr = 0.f, ctl = 0.f, ctr = 0.f, cbl = 0.f, cbr = 0.f;
            if (MODE == 1) {
                int h = hw / 14, w = hw - (hw / 14) * 14;
                pt = (h == 0) ? 1.f : 0.f;  pb = (h == 13) ? 1.f : 0.f;
                pl = (w == 0) ? 1.f : 0.f;  pr = (w == 13) ? 1.f : 0.f;
                ctl = pt * pl; ctr = pt * pr; cbl = pb * pl; cbr = pb * pr;
                float miss = 3.f * (pt + pb + pl + pr) - (ctl + ctr + cbl + cbr);
                constterm = cK * (256.f * (9.f - miss));
            } else {
                constterm = cK * (float)K;
            }
#pragma unroll
            for (int ni = 0; ni < 2; ni++) {
                float rsum = rr0[ni];
                if (MODE == 1)
                    rsum -= pt * t8v[ni][0] + pb * t8v[ni][1] + pl * t8v[ni][2] + pr * t8v[ni][3]
                          - ctl * t8v[ni][4] - ctr * t8v[ni][5] - cbl * t8v[ni][6] - cbr * t8v[ni][7];
                float v = caa * (float)acc[mi][ni][reg] + cR * rsum + cC * cj + constterm;
                outNHWC[(size_t)j * 256 + cco[ni]] = v;
                ssm[ni] += v;
                smnv[ni] = fminf(smnv[ni], v);
                smxv[ni] = fmaxf(smxv[ni], v);
            }
        }
#pragma unroll
    for (int ni = 0; ni < 2; ni++) {
        float s = ssm[ni], mn = smnv[ni], mx = smxv[ni];
        s += __shfl_xor(s, 16, 64); s += __shfl_xor(s, 32, 64);
        mn = fminf(mn, __shfl_xor(mn, 16, 64)); mn = fminf(mn, __shfl_xor(mn, 32, 64));
        mx = fmaxf(mx, __shfl_xor(mx, 16, 64)); mx = fmaxf(mx, __shfl_xor(mx, 32, 64));
        if (kq == 0) {
            int co = cco[ni];
            atomicAdd(&s_sum[co], s);
            atomicMin(&s_mn[co], encf(mn));
            atomicMax(&s_mx[co], encf(mx));
        }
    }
}

// ---------------- conv3: i8 MFMA, A=weights (M=128 co), B=acts (N=64 img), K=256 single-stage ----------------
__global__ __launch_bounds__(256, 2) void k_conv3(const signed char* __restrict__ Wts,
                                                  const signed char* __restrict__ Zc,
                                                  const float* __restrict__ R, const float* __restrict__ Cj,
                                                  const float* __restrict__ pw, const float* __restrict__ pz,
                                                  float* __restrict__ out,
                                                  float* __restrict__ s_sum, unsigned* __restrict__ s_mn,
                                                  unsigned* __restrict__ s_mx) {
    __shared__ __align__(16) signed char As[32768];   // 128 rows x 256B
    __shared__ __align__(16) signed char Bs[16384];   // 64 rows x 256B
    int tid = threadIdx.x, lane = tid & 63, wave = tid >> 6;
    int wm = wave >> 1, wn = wave & 1;
    int jb = blockIdx.x * 64, cob = blockIdx.y * 128;
    int sr = tid >> 4, spos = tid & 15, sc = spos ^ (sr & 7);
#pragma unroll
    for (int q = 0; q < 8; q++)
        glds16(Wts + (size_t)(cob + q * 16 + sr) * 256 + sc * 16, &As[(q * 16 + sr) * 256 + spos * 16]);
#pragma unroll
    for (int q = 0; q < 4; q++)
        glds16(Zc + (size_t)(jb + q * 16 + sr) * 256 + sc * 16, &Bs[(q * 16 + sr) * 256 + spos * 16]);
    __syncthreads();

    int4v acc[4][2];
#pragma unroll
    for (int mi = 0; mi < 4; mi++)
#pragma unroll
        for (int ni = 0; ni < 2; ni++) acc[mi][ni] = (int4v)0;

    int l15 = lane & 15, kq = lane >> 4, sw = l15 & 7;
#pragma unroll
    for (int kc = 0; kc < 4; kc++) {
        int col = ((kc * 4 + kq) ^ sw) << 4;
        int4v a[4], bb[2];
#pragma unroll
        for (int mi = 0; mi < 4; mi++)
            a[mi] = *(const int4v*)&As[(wm * 64 + mi * 16 + l15) * 256 + col];
#pragma unroll
        for (int ni = 0; ni < 2; ni++)
            bb[ni] = *(const int4v*)&Bs[(wn * 32 + ni * 16 + l15) * 256 + col];
#pragma unroll
        for (int mi = 0; mi < 4; mi++)
#pragma unroll
            for (int ni = 0; ni < 2; ni++)
                acc[mi][ni] = __builtin_amdgcn_mfma_i32_16x16x64_i8(a[mi], bb[ni], acc[mi][ni], 0, 0, 0);
    }

    float aw = pw[1], bw = pw[0] + 128.f * pw[1];
    float az = pz[1], bz = pz[0] + 128.f * pz[1];
    float caa = aw * az, cR = aw * bz, cC = bw * az, cK = bw * bz;
    int jj[2], nn[2], hh[2]; float cjv[2];
#pragma unroll
    for (int ni = 0; ni < 2; ni++) {
        jj[ni] = jb + wn * 32 + ni * 16 + l15;
        nn[ni] = jj[ni] / 196; hh[ni] = jj[ni] - nn[ni] * 196;
        cjv[ni] = Cj[jj[ni]];
    }
#pragma unroll
    for (int mi = 0; mi < 4; mi++)
#pragma unroll
        for (int reg = 0; reg < 4; reg++) {
            int co = cob + wm * 64 + mi * 16 + kq * 4 + reg;
            float rsum = R[co];
            float v0 = caa * (float)acc[mi][0][reg] + cR * rsum + cC * cjv[0] + cK * 256.f;
            float v1 = caa * (float)acc[mi][1][reg] + cR * rsum + cC * cjv[1] + cK * 256.f;
            out[((size_t)nn[0] * 1024 + co) * 196 + hh[0]] = v0;
            out[((size_t)nn[1] * 1024 + co) * 196 + hh[1]] = v1;
            float ls = v0 + v1, lmn = fminf(v0, v1), lmx = fmaxf(v0, v1);
            ls += __shfl_xor(ls, 1, 64);  lmn = fminf(lmn, __shfl_xor(lmn, 1, 64)); lmx = fmaxf(lmx, __shfl_xor(lmx, 1, 64));
            ls += __shfl_xor(ls, 2, 64);  lmn = fminf(lmn, __shfl_xor(lmn, 2, 64)); lmx = fmaxf(lmx, __shfl_xor(lmx, 2, 64));
            ls += __shfl_xor(ls, 4, 64);  lmn = fminf(lmn, __shfl_xor(lmn, 4, 64)); lmx = fmaxf(lmx, __shfl_xor(lmx, 4, 64));
            ls += __shfl_xor(ls, 8, 64);  lmn = fminf(lmn, __shfl_xor(lmn, 8, 64)); lmx = fmaxf(lmx, __shfl_xor(lmx, 8, 64));
            if (l15 == 0) {
                atomicAdd(&s_sum[co], ls);
                atomicMin(&s_mn[co], encf(lmn));
                atomicMax(&s_mx[co], encf(lmx));
            }
        }
}

// ---------------- finalize range_norm from atomic stats ----------------
__global__ __launch_bounds__(256) void k_finnorm(int C, const float* __restrict__ gamma, const float* __restrict__ beta,
                                                 const float* __restrict__ sum_i, const unsigned* __restrict__ mn_e,
                                                 const unsigned* __restrict__ mx_e, float* mean_o, float* sg_o,
                                                 float* qp, float scale_fix) {
    int tid = threadIdx.x;
    int lane = tid & 63, w = tid >> 6;
    __shared__ float sa[4], sb[4];
    float gmn = INFINITY, gmx = -INFINITY;
    for (int c = tid; c < C; c += 256) { float g = gamma[c]; gmn = fminf(gmn, g); gmx = fmaxf(gmx, g); }
    for (int o = 32; o; o >>= 1) { gmn = fminf(gmn, __shfl_down(gmn, o, 64)); gmx = fmaxf(gmx, __shfl_down(gmx, o, 64)); }
    if (lane == 0) { sa[w] = gmn; sb[w] = gmx; }
    __syncthreads();
    gmn = fminf(fminf(sa[0], sa[1]), fminf(sa[2], sa[3]));
    gmx = fmaxf(fmaxf(sb[0], sb[1]), fmaxf(sb[2], sb[3]));
    float gsc = fmaxf((gmx - gmn) / 255.0f, 1e-8f);
    __syncthreads();
    float qmn = INFINITY, qmx = -INFINITY;
    for (int c = tid; c < C; c += 256) {
        float mean = sum_i[c] / 12544.0f;
        float cmn = decf(mn_e[c]), cmx = decf(mx_e[c]);
        float rng = cmx - cmn;
        float qg = fqv(gamma[c], gmn, gsc);
        float s = qg / (rng * scale_fix + 1e-5f);
        mean_o[c] = mean; sg_o[c] = s;
        float b = beta[c];
        float lo = (cmn - mean) * s + b;
        float hi = (cmx - mean) * s + b;
        qmn = fminf(qmn, fminf(lo, hi));
        qmx = fmaxf(qmx, fmaxf(lo, hi));
    }
    for (int o = 32; o; o >>= 1) { qmn = fminf(qmn, __shfl_down(qmn, o, 64)); qmx = fmaxf(qmx, __shfl_down(qmx, o, 64)); }
    if (lane == 0) { sa[w] = qmn; sb[w] = qmx; }
    __syncthreads();
    if (tid == 0) {
        qmn = fminf(fminf(sa[0], sa[1]), fminf(sa[2], sa[3]));
        qmx = fmaxf(fmaxf(sb[0], sb[1]), fmaxf(sb[2], sb[3]));
        qp[0] = qmn;
        qp[1] = fmaxf((qmx - qmn) / 255.0f, 1e-8f);
    }
}

// ---------------- final: out = fq(x) + fq(norm3(out3)) in place ----------------
__global__ __launch_bounds__(256) void k_final(const float* __restrict__ x, float* __restrict__ out,
                                               const float* __restrict__ mean, const float* __restrict__ sg,
                                               const float* __restrict__ beta, const float* __restrict__ sf,
                                               const float* __restrict__ qp) {
    float xmn = sf[8], xsc = sf[9];
    float qmn = qp[0], qsc = qp[1];
    const float4* xp = (const float4*)x;
    float4* yp = (float4*)out;
    int n4 = 12845056 / 4;
    int i = blockIdx.x * blockDim.x + threadIdx.x;
    int str = gridDim.x * blockDim.x;
    for (; i < n4; i += str) {
        int e = i * 4;
        int c = (e / 196) & 1023;
        float m = mean[c], s = sg[c], b = beta[c];
        float4 xv = xp[i], ov = yp[i], r;
        r.x = fqv(xv.x, xmn, xsc) + fqv((ov.x - m) * s + b, qmn, qsc);
        r.y = fqv(xv.y, xmn, xsc) + fqv((ov.y - m) * s + b, qmn, qsc);
        r.z = fqv(xv.z, xmn, xsc) + fqv((ov.z - m) * s + b, qmn, qsc);
        r.w = fqv(xv.w, xmn, xsc) + fqv((ov.w - m) * s + b, qmn, qsc);
        yp[i] = r;
    }
}

extern "C" void kernel_launch(void* const* d_in, const int* in_sizes, int n_in,
                              void* d_out, int out_size, void* d_ws, size_t ws_size,
                              hipStream_t stream) {
    const float* x  = (const float*)d_in[0];
    const float* w1 = (const float*)d_in[1];
    const float* g1 = (const float*)d_in[2];
    const float* b1 = (const float*)d_in[3];
    const float* w2 = (const float*)d_in[4];
    const float* g2 = (const float*)d_in[5];
    const float* b2 = (const float*)d_in[6];
    const float* w3 = (const float*)d_in[7];
    const float* g3 = (const float*)d_in[8];
    const float* b3 = (const float*)d_in[9];
    float* out = (float*)d_out;

    float* W = (float*)d_ws;
    float* OUT = W + OF_OUT;
    signed char* xc  = (signed char*)(W + OF_XC);
    signed char* z1p = (signed char*)(W + OF_Z1P);
    signed char* z2c = (signed char*)(W + OF_Z2C);
    signed char* wq1 = (signed char*)(W + OF_WQ1);
    signed char* wq2 = (signed char*)(W + OF_WQ2);
    signed char* wq3 = (signed char*)(W + OF_WQ3);
    float* R1 = W + OF_R1; float* R2 = W + OF_R2; float* R3 = W + OF_R3;
    float* T2 = W + OF_T2;
    float* CX = W + OF_CX; float* U2 = W + OF_U2; float* V2 = W + OF_V2; float* CZ = W + OF_CZ;
    float* AS = W + OF_AS;
    float* sum1 = AS, *sum2 = AS + 256, *sum3 = AS + 512;
    unsigned* mx1 = (unsigned*)(AS + 1536); unsigned* mx2 = (unsigned*)(AS + 1792); unsigned* mx3 = (unsigned*)(AS + 2048);
    unsigned* mn1 = (unsigned*)(AS + 3072); unsigned* mn2 = (unsigned*)(AS + 3328); unsigned* mn3 = (unsigned*)(AS + 3584);
    float* S = W + OF_ST;
    unsigned* Su = (unsigned*)S;
    float* MS = W + OF_MS;
    float* mean1 = MS, *sg1 = MS + 256, *mean2 = MS + 512, *sg2 = MS + 768, *mean3 = MS + 1024, *sg3 = MS + 2048;

    const float scale_fix =
        (float)((0.5 * 0.35) * (1.0 + sqrt(M_PI * log(4.0))) / sqrt(2.0 * log(12544.0)));

    // init scratch (each region rewritten/cleared every launch)
    hipMemsetAsync(AS, 0, 3072 * 4, stream);            // sums + max-enc
    hipMemsetAsync(AS + 3072, 0xFF, 1536 * 4, stream);  // min-enc
    hipMemsetAsync(CX, 0, 12544 * 4, stream);
    hipMemsetAsync(U2, 0, 16384 * 4, stream);
    hipMemsetAsync(z1p, 0, 4194304, stream);

    // fq params for x, w1, w2, w3
    k_init<<<1, 64, 0, stream>>>(Su);
    k_minmax<<<1024, 256, 0, stream>>>((const float4*)x,  12845056 / 4, Su + 0);
    k_minmax<<<64,   256, 0, stream>>>((const float4*)w1, 262144 / 4,  Su + 2);
    k_minmax<<<128,  256, 0, stream>>>((const float4*)w2, 589824 / 4,  Su + 4);
    k_minmax<<<64,   256, 0, stream>>>((const float4*)w3, 262144 / 4,  Su + 6);
    k_fqparams<<<1, 64, 0, stream>>>(Su, S);

    // weight codes + reductions
    k_wcode11<<<256,  256, 0, stream>>>(w1, S + 11, wq1, R1, 1024);
    k_wcode11<<<1024, 256, 0, stream>>>(w3, S + 17, wq3, R3, 256);
    k_wcode33<<<256,  256, 0, stream>>>(w2, S + 14, wq2, R2, T2);

    // x -> NHWC i8 codes + CX
    k_code0<<<dim3(7, 4, 64), 256, 0, stream>>>(x, xc, S + 8, CX);

    // conv1 -> OUT NHWC + stage1 stats
    k_conv12<0><<<dim3(98, 4), 256, 0, stream>>>(xc, wq1, R1, nullptr, CX, S + 11, S + 8, OUT, 1024,
                                                 sum1, mn1, mx1);
    k_finnorm<<<1, 256, 0, stream>>>(256, g1, b1, sum1, mn1, mx1, mean1, sg1, S + 20, scale_fix);
    k_codeE<1><<<784, 256, 0, stream>>>(OUT, z1p, mean1, sg1, b1, S + 20, U2);
    k_v2<<<49, 256, 0, stream>>>(U2, V2);

    // conv2 -> OUT NHWC + stage2 stats
    k_conv12<1><<<dim3(98, 4), 256, 0, stream>>>(z1p, wq2, R2, T2, V2, S + 14, S + 20, OUT, 2304,
                                                 sum2, mn2, mx2);
    k_finnorm<<<1, 256, 0, stream>>>(256, g2, b2, sum2, mn2, mx2, mean2, sg2, S + 23, scale_fix);
    k_codeE<0><<<784, 256, 0, stream>>>(OUT, z2c, mean2, sg2, b2, S + 23, CZ);

    // conv3 -> d_out NCHW + stage3 stats
    k_conv3<<<dim3(196, 8), 256, 0, stream>>>(wq3, z2c, R3, CZ, S + 17, S + 23, out, sum3, mn3, mx3);
    k_finnorm<<<1, 256, 0, stream>>>(1024, g3, b3, sum3, mn3, mx3, mean3, sg3, S + 26, scale_fix);
    k_final<<<2048, 256, 0, stream>>>(x, out, mean3, sg3, b3, S, S + 26);
}

// Round 5
// 282.059 us; speedup vs baseline: 1.6365x; 1.3577x over previous
//
#include <hip/hip_runtime.h>
#include <math.h>

#ifndef M_PI
#define M_PI 3.14159265358979323846
#endif

// Shapes: x [64,1024,14,14]; w1 [256,1024]; w2 [256,256,3,3]; w3 [1024,256]
#define NB   64
#define NCOL 12544

typedef __attribute__((ext_vector_type(4))) int int4v;

// ---------------- workspace layout (float offsets) ----------------
static const size_t OF_OUT = 0;            // conv1/conv2 fp32 NHWC out [12544][256]
static const size_t OF_XC  = 3211264;      // x codes i8 NHWC [64][196][1024]
static const size_t OF_Z1P = 6422528;      // z1 codes i8 padded [64][16][16][256]
static const size_t OF_Z2C = 7471104;      // z2 codes i8 [12544][256]
static const size_t OF_WQ1 = 8273920;      // w1 codes i8 [256][1024]
static const size_t OF_WQ2 = 8339456;      // w2 codes i8 [256][9*256]
static const size_t OF_WQ3 = 8486912;      // w3 codes i8 [1024][256]
static const size_t OF_R1  = 8552448;
static const size_t OF_R2  = 8552704;
static const size_t OF_R3  = 8552960;
static const size_t OF_T2  = 8553984;      // 256*8 tap aggregates
static const size_t OF_CX  = 8556032;      // 12544
static const size_t OF_U2  = 8568576;      // 16384
static const size_t OF_V2  = 8584960;      // 12544
static const size_t OF_CZ  = 8597504;      // 12544
static const size_t OF_P1  = 8610048;      // stage1 partials: sum[98*256], mn, mx
static const size_t OF_P2  = 8685312;      // stage2 partials
static const size_t OF_P3  = 8760576;      // stage3 partials: sum[98*1024], mn, mx
static const size_t OF_PMM = 9061632;      // minmax partials: x@0 (1024*2), w1@2048, w2@2176, w3@2432
static const size_t OF_RS  = 9064192;      // reduced stats (4608)
static const size_t OF_ST  = 9068800;      // 64 misc floats (fq params)
static const size_t OF_MS  = 9068864;      // mean/sg arrays (3072)

__device__ __forceinline__ float fqv(float v, float mn, float sc) {
    float t = (v - mn) / sc;
    t = fminf(fmaxf(t, 0.0f), 255.0f);
    return rintf(t) * sc + mn;
}
// centered code (integer-valued in [-128,127])
__device__ __forceinline__ float codef(float v, float mn, float sc) {
    float t = (v - mn) / sc;
    t = fminf(fmaxf(t, 0.0f), 255.0f);
    return rintf(t) - 128.0f;
}
__device__ __forceinline__ unsigned short f2bf(float f) { return (unsigned short)(__float_as_uint(f) >> 16); }
__device__ __forceinline__ float bf2f(unsigned short u) { return __uint_as_float(((unsigned)u) << 16); }
__device__ __forceinline__ int pack4(float a, float b, float c, float d) {
    return (int)(unsigned char)(signed char)(int)a | ((int)(unsigned char)(signed char)(int)b << 8) |
           ((int)(unsigned char)(signed char)(int)c << 16) | ((int)(unsigned char)(signed char)(int)d << 24);
}
__device__ __forceinline__ void glds16(const void* g, void* l) {
    __builtin_amdgcn_global_load_lds((const __attribute__((address_space(1))) unsigned int*)g,
                                     (__attribute__((address_space(3))) unsigned int*)l, 16, 0, 0);
}

// ---------------- fused min/max over 4 tensors -> per-block partials (no atomics) ----------------
__global__ __launch_bounds__(256) void k_minmax_all(const float4* __restrict__ x, const float4* __restrict__ w1,
                                                    const float4* __restrict__ w2, const float4* __restrict__ w3,
                                                    float* __restrict__ Pmm) {
    int b = blockIdx.x;
    const float4* p; int lb, nb, n4, base;
    if (b < 1024)      { p = x;  lb = b;        nb = 1024; n4 = 3211264; base = 0; }
    else if (b < 1088) { p = w1; lb = b - 1024; nb = 64;   n4 = 65536;   base = 2048; }
    else if (b < 1216) { p = w2; lb = b - 1088; nb = 128;  n4 = 147456;  base = 2176; }
    else               { p = w3; lb = b - 1216; nb = 64;   n4 = 65536;   base = 2432; }
    float mn = INFINITY, mx = -INFINITY;
    for (int i = lb * 256 + threadIdx.x; i < n4; i += nb * 256) {
        float4 v = p[i];
        mn = fminf(mn, fminf(fminf(v.x, v.y), fminf(v.z, v.w)));
        mx = fmaxf(mx, fmaxf(fmaxf(v.x, v.y), fmaxf(v.z, v.w)));
    }
    for (int o = 32; o; o >>= 1) {
        mn = fminf(mn, __shfl_down(mn, o, 64));
        mx = fmaxf(mx, __shfl_down(mx, o, 64));
    }
    __shared__ float smn[4], smx[4];
    int lane = threadIdx.x & 63, w = threadIdx.x >> 6;
    if (lane == 0) { smn[w] = mn; smx[w] = mx; }
    __syncthreads();
    if (threadIdx.x == 0) {
        for (int i = 1; i < 4; i++) { mn = fminf(mn, smn[i]); mx = fmaxf(mx, smx[i]); }
        Pmm[base + lb * 2]     = mn;
        Pmm[base + lb * 2 + 1] = mx;
    }
}

// reduce minmax partials -> (mn, scale) for x,w1,w2,w3
__global__ __launch_bounds__(256) void k_fqparams2(const float* __restrict__ Pmm, float* __restrict__ sf) {
    __shared__ float sa[4], sb[4];
    int t = threadIdx.x, lane = t & 63, w = t >> 6;
    const int nbs[4]   = {1024, 64, 128, 64};
    const int bases[4] = {0, 2048, 2176, 2432};
    for (int ten = 0; ten < 4; ten++) {
        float mn = INFINITY, mx = -INFINITY;
        for (int i = t; i < nbs[ten]; i += 256) {
            mn = fminf(mn, Pmm[bases[ten] + 2 * i]);
            mx = fmaxf(mx, Pmm[bases[ten] + 2 * i + 1]);
        }
        for (int o = 32; o; o >>= 1) {
            mn = fminf(mn, __shfl_down(mn, o, 64));
            mx = fmaxf(mx, __shfl_down(mx, o, 64));
        }
        if (lane == 0) { sa[w] = mn; sb[w] = mx; }
        __syncthreads();
        if (t == 0) {
            mn = fminf(fminf(sa[0], sa[1]), fminf(sa[2], sa[3]));
            mx = fmaxf(fmaxf(sb[0], sb[1]), fmaxf(sb[2], sb[3]));
            sf[8 + 3 * ten] = mn;
            sf[9 + 3 * ten] = fmaxf((mx - mn) / 255.0f, 1e-8f);
        }
        __syncthreads();
    }
}

// ---------------- fused weight coding (w1 | w3 | w2) ----------------
__global__ __launch_bounds__(256) void k_wcode_all(const float* __restrict__ w1, const float* __restrict__ w2,
                                                   const float* __restrict__ w3, const float* __restrict__ sf,
                                                   signed char* __restrict__ wq1, signed char* __restrict__ wq2,
                                                   signed char* __restrict__ wq3,
                                                   float* __restrict__ R1, float* __restrict__ R2,
                                                   float* __restrict__ R3, float* __restrict__ T8) {
    __shared__ float sh[64];
    int b = blockIdx.x, t = threadIdx.x;
    int lane = t & 63, wv = t >> 6;
    if (b < 1280) {
        // 1x1 weight coding
        const float* w; signed char* wc; float* R; int K, co; const float* pw;
        if (b < 256) { w = w1; wc = wq1; R = R1; K = 1024; co = b; pw = sf + 11; }
        else         { w = w3; wc = wq3; R = R3; K = 256;  co = b - 256; pw = sf + 17; }
        float mn = pw[0], s = pw[1];
        float sum = 0.f;
        for (int k0 = t * 4; k0 < K; k0 += 1024) {
            float4 v = *(const float4*)&w[(size_t)co * K + k0];
            float c0 = codef(v.x, mn, s), c1 = codef(v.y, mn, s), c2 = codef(v.z, mn, s), c3 = codef(v.w, mn, s);
            *(int*)&wc[(size_t)co * K + k0] = pack4(c0, c1, c2, c3);
            sum += c0 + c1 + c2 + c3;
        }
        for (int o = 32; o; o >>= 1) sum += __shfl_down(sum, o, 64);
        if (lane == 0) sh[wv] = sum;
        __syncthreads();
        if (t == 0) R[co] = sh[0] + sh[1] + sh[2] + sh[3];
    } else {
        // 3x3 weight coding: codes [co][p*256+ci], R2[co], T8[co][8]
        int co = b - 1280, ci = t;
        float mn = sf[14], s = sf[15];
        float tp[9];
#pragma unroll
        for (int p = 0; p < 9; p++) {
            float c = codef(w2[((size_t)co * 256 + ci) * 9 + p], mn, s);
            wq2[(size_t)co * 2304 + p * 256 + ci] = (signed char)(int)c;
            tp[p] = c;
        }
        float* red = sh;      // [4][9]
        float* sT = sh + 40;  // [9]
#pragma unroll
        for (int p = 0; p < 9; p++) {
            float v = tp[p];
            for (int o = 32; o; o >>= 1) v += __shfl_down(v, o, 64);
            if (lane == 0) red[wv * 9 + p] = v;
        }
        __syncthreads();
        if (ci < 9) sT[ci] = red[ci] + red[9 + ci] + red[18 + ci] + red[27 + ci];
        __syncthreads();
        if (ci == 0) {
            float T0 = sT[0], T1 = sT[1], T2 = sT[2], T3 = sT[3],
                  T5 = sT[5], T6 = sT[6], T7 = sT[7], T8v = sT[8];
            R2[co] = T0 + T1 + T2 + T3 + sT[4] + T5 + T6 + T7 + T8v;
            float* o = &T8[co * 8];
            o[0] = T0 + T1 + T2;   // top
            o[1] = T6 + T7 + T8v;  // bot
            o[2] = T0 + T3 + T6;   // left
            o[3] = T2 + T5 + T8v;  // right
            o[4] = T0; o[5] = T2; o[6] = T6; o[7] = T8v;
        }
    }
}

// ---------------- x NCHW fp32 -> NHWC i8 codes + CX rowsum ----------------
__global__ __launch_bounds__(256) void k_code0(const float* __restrict__ x, signed char* __restrict__ dst,
                                               const float* __restrict__ qp, float* __restrict__ CX) {
    __shared__ unsigned short lt[28][264];
    int n = blockIdx.z, hw0 = blockIdx.x * 28, cq = blockIdx.y * 256;
    int t = threadIdx.x;
    float qmn = qp[0], qsc = qp[1];
    const float* sp = x + ((size_t)n * 1024 + cq) * 196 + hw0;
    for (int i = t; i < 7168; i += 256) {
        int c = i / 28, hw = i - c * 28;
        lt[hw][c] = f2bf(codef(sp[(size_t)c * 196 + hw], qmn, qsc));
    }
    __syncthreads();
    int lane = t & 63, wv = t >> 6;
    int c0 = lane * 4;
#pragma unroll
    for (int s = 0; s < 7; s++) {
        int i = s * 4 + wv;
        int pk = pack4(bf2f(lt[i][c0]), bf2f(lt[i][c0 + 1]), bf2f(lt[i][c0 + 2]), bf2f(lt[i][c0 + 3]));
        *(int*)&dst[((size_t)n * 196 + hw0 + i) * 1024 + cq + c0] = pk;
    }
    for (int i = wv; i < 28; i += 4) {
        float s = bf2f(lt[i][lane]) + bf2f(lt[i][lane + 64]) +
                  bf2f(lt[i][lane + 128]) + bf2f(lt[i][lane + 192]);
        for (int o = 32; o; o >>= 1) s += __shfl_down(s, o, 64);
        if (lane == 0) atomicAdd(&CX[n * 196 + hw0 + i], s);
    }
}

// ---------------- NHWC elementwise norm+quant -> i8 codes + rowsum ----------------
template <int PAD>
__global__ __launch_bounds__(256) void k_codeE(const float* __restrict__ src, signed char* __restrict__ dst,
                                               const float* __restrict__ mean, const float* __restrict__ sg,
                                               const float* __restrict__ beta, const float* __restrict__ qp,
                                               float* __restrict__ rowsum) {
    int t = threadIdx.x, lane = t & 63, wv = t >> 6;
    int c4 = lane * 4;
    float4 m4 = *(const float4*)&mean[c4];
    float4 s4 = *(const float4*)&sg[c4];
    float4 b4 = *(const float4*)&beta[c4];
    float qmn = qp[0], qsc = qp[1];
#pragma unroll
    for (int r = 0; r < 4; r++) {
        int j = blockIdx.x * 16 + wv * 4 + r;
        float4 v = *(const float4*)&src[(size_t)j * 256 + c4];
        float c0 = codef((v.x - m4.x) * s4.x + b4.x, qmn, qsc);
        float c1 = codef((v.y - m4.y) * s4.y + b4.y, qmn, qsc);
        float c2 = codef((v.z - m4.z) * s4.z + b4.z, qmn, qsc);
        float c3 = codef((v.w - m4.w) * s4.w + b4.w, qmn, qsc);
        int n = j / 196, hw = j - n * 196, h = hw / 14, w = hw - (hw / 14) * 14;
        size_t di;
        if (PAD) di = (((size_t)n * 16 + h + 1) * 16 + (w + 1)) * 256 + c4;
        else     di = (size_t)j * 256 + c4;
        *(int*)&dst[di] = pack4(c0, c1, c2, c3);
        float s = c0 + c1 + c2 + c3;
        for (int o = 32; o; o >>= 1) s += __shfl_down(s, o, 64);
        if (lane == 0) {
            if (PAD) rowsum[((size_t)n * 16 + h + 1) * 16 + (w + 1)] = s;
            else     rowsum[j] = s;
        }
    }
}

// V2[j] = 9-tap sum of U2 (padded [n][16][16])
__global__ __launch_bounds__(256) void k_v2(const float* __restrict__ U, float* __restrict__ V) {
    int j = blockIdx.x * 256 + threadIdx.x;
    if (j >= NCOL) return;
    int n = j / 196, hw = j - n * 196, h = hw / 14, w = hw - (hw / 14) * 14;
    const float* u = U + (size_t)n * 256;
    float s = 0.f;
#pragma unroll
    for (int r = 0; r < 3; r++)
#pragma unroll
        for (int c = 0; c < 3; c++) s += u[(h + r) * 16 + (w + c)];
    V[j] = s;
}

// ---------------- conv1/conv2: i8 MFMA, A=acts (M=128 j), B=weights (N=64 co), BK=128, dbuf ----------------
// Output NHWC fp32 + per-block partial stats (no global atomics).
template <int MODE>
__global__ __launch_bounds__(256, 2) void k_conv12(const signed char* __restrict__ Acts,
                                                   const signed char* __restrict__ Wts,
                                                   const float* __restrict__ R, const float* __restrict__ T8,
                                                   const float* __restrict__ Cj,
                                                   const float* __restrict__ pw, const float* __restrict__ pz,
                                                   float* __restrict__ outNHWC, int K,
                                                   float* __restrict__ Ps, float* __restrict__ Pn,
                                                   float* __restrict__ Px) {
    __shared__ __align__(16) signed char As[2 * 16384];   // 2 x 128 rows x 128B
    __shared__ __align__(16) signed char Bs[2 * 8192];    // 2 x 64 rows x 128B
    __shared__ float Lst[2][64][3];
    int tid = threadIdx.x, lane = tid & 63, wave = tid >> 6;
    int wm = wave >> 1, wn = wave & 1;
    int jb = blockIdx.x * 128, cob = blockIdx.y * 64;
    int sr = tid >> 3, spos = tid & 7, sc = spos ^ (sr & 7);

    const signed char* aq[4];
#pragma unroll
    for (int q = 0; q < 4; q++) {
        int j = jb + q * 32 + sr;
        if (MODE == 0) aq[q] = Acts + (size_t)j * K + sc * 16;
        else {
            int n = j / 196, hw = j - n * 196, h = hw / 14, w = hw - (hw / 14) * 14;
            aq[q] = Acts + (((size_t)n * 16 + h) * 16 + w) * 256 + sc * 16;
        }
    }
    const signed char* bq[2];
#pragma unroll
    for (int q = 0; q < 2; q++) bq[q] = Wts + (size_t)(cob + q * 32 + sr) * K + sc * 16;

    int4v acc[4][2];
#pragma unroll
    for (int mi = 0; mi < 4; mi++)
#pragma unroll
        for (int ni = 0; ni < 2; ni++) acc[mi][ni] = (int4v)0;

    int nk = K >> 7;
    auto stage = [&](int b, int ks) {
        size_t koA;
        if (MODE == 0) koA = (size_t)ks << 7;
        else {
            int k = ks << 7;
            int p = k >> 8, kin = k & 255;
            int rr = p / 3, ss = p - 3 * rr;
            koA = (size_t)(rr * 16 + ss) * 256 + kin;
        }
#pragma unroll
        for (int q = 0; q < 4; q++)
            glds16(aq[q] + koA, &As[b * 16384 + (q * 32 + sr) * 128 + spos * 16]);
#pragma unroll
        for (int q = 0; q < 2; q++)
            glds16(bq[q] + ((size_t)ks << 7), &Bs[b * 8192 + (q * 32 + sr) * 128 + spos * 16]);
    };

    int l15 = lane & 15, kq = lane >> 4, sw = l15 & 7;
    stage(0, 0);
    for (int ks = 0; ks < nk; ks++) {
        __syncthreads();
        if (ks + 1 < nk) stage((ks + 1) & 1, ks + 1);
        int b = ks & 1;
#pragma unroll
        for (int kc = 0; kc < 2; kc++) {
            int col = ((kc * 4 + kq) ^ sw) << 4;
            int4v a[4], bb[2];
#pragma unroll
            for (int mi = 0; mi < 4; mi++)
                a[mi] = *(const int4v*)&As[b * 16384 + (wm * 64 + mi * 16 + l15) * 128 + col];
#pragma unroll
            for (int ni = 0; ni < 2; ni++)
                bb[ni] = *(const int4v*)&Bs[b * 8192 + (wn * 32 + ni * 16 + l15) * 128 + col];
#pragma unroll
            for (int mi = 0; mi < 4; mi++)
#pragma unroll
                for (int ni = 0; ni < 2; ni++)
                    acc[mi][ni] = __builtin_amdgcn_mfma_i32_16x16x64_i8(a[mi], bb[ni], acc[mi][ni], 0, 0, 0);
        }
    }

    // epilogue: value = aw*az*S + aw*bz*(R-PT) + bw*az*Cj + bw*bz*Kvalid ; NHWC store + partial stats
    float aw = pw[1], bw = pw[0] + 128.f * pw[1];
    float az = pz[1], bz = pz[0] + 128.f * pz[1];
    float caa = aw * az, cR = aw * bz, cC = bw * az, cK = bw * bz;
    int cco[2]; float rr0[2]; float t8v[2][8];
#pragma unroll
    for (int ni = 0; ni < 2; ni++) {
        cco[ni] = cob + wn * 32 + ni * 16 + l15;
        rr0[ni] = R[cco[ni]];
        if (MODE == 1) {
#pragma unroll
            for (int p = 0; p < 8; p++) t8v[ni][p] = T8[cco[ni] * 8 + p];
        }
    }
    float ssm[2] = {0.f, 0.f}, smnv[2] = {INFINITY, INFINITY}, smxv[2] = {-INFINITY, -INFINITY};
#pragma unroll
    for (int mi = 0; mi < 4; mi++)
#pragma unroll
        for (int reg = 0; reg < 4; reg++) {
            int j = jb + wm * 64 + mi * 16 + kq * 4 + reg;
            int n = j / 196, hw = j - n * 196;
            float cj = Cj[j];
            float constterm;
            float pt = 0.f, pb = 0.f, pl = 0.f, pr = 0.f, ctl = 0.f, ctr = 0.f, cbl = 0.f, cbr = 0.f;
            if (MODE == 1) {
                int h = hw / 14, w = hw - (hw / 14) * 14;
                pt = (h == 0) ? 1.f : 0.f;  pb = (h == 13) ? 1.f : 0.f;
                pl = (w == 0) ? 1.f : 0.f;  pr = (w == 13) ? 1.f : 0.f;
                ctl = pt * pl; ctr = pt * pr; cbl = pb * pl; cbr = pb * pr;
                float miss = 3.f * (pt + pb + pl + pr) - (ctl + ctr + cbl + cbr);
                constterm = cK * (256.f * (9.f - miss));
            } else {
                constterm = cK * (float)K;
            }
#pragma unroll
            for (int ni = 0; ni < 2; ni++) {
                float rsum = rr0[ni];
                if (MODE == 1)
                    rsum -= pt * t8v[ni][0] + pb * t8v[ni][1] + pl * t8v[ni][2] + pr * t8v[ni][3]
                          - ctl * t8v[ni][4] - ctr * t8v[ni][5] - cbl * t8v[ni][6] - cbr * t8v[ni][7];
                float v = caa * (float)acc[mi][ni][reg] + cR * rsum + cC * cj + constterm;
                outNHWC[(size_t)j * 256 + cco[ni]] = v;
                ssm[ni] += v;
                smnv[ni] = fminf(smnv[ni], v);
                smxv[ni] = fmaxf(smxv[ni], v);
            }
        }
#pragma unroll
    for (int ni = 0; ni < 2; ni++) {
        float s = ssm[ni], mn = smnv[ni], mx = smxv[ni];
        s += __shfl_xor(s, 16, 64); s += __shfl_xor(s, 32, 64);
        mn = fminf(mn, __shfl_xor(mn, 16, 64)); mn = fminf(mn, __shfl_xor(mn, 32, 64));
        mx = fmaxf(mx, __shfl_xor(mx, 16, 64)); mx = fmaxf(mx, __shfl_xor(mx, 32, 64));
        if (kq == 0) {
            int cl = wn * 32 + ni * 16 + l15;
            Lst[wm][cl][0] = s; Lst[wm][cl][1] = mn; Lst[wm][cl][2] = mx;
        }
    }
    __syncthreads();
    if (tid < 64) {
        float s  = Lst[0][tid][0] + Lst[1][tid][0];
        float mn = fminf(Lst[0][tid][1], Lst[1][tid][1]);
        float mx = fmaxf(Lst[0][tid][2], Lst[1][tid][2]);
        int idx = blockIdx.x * 256 + cob + tid;
        Ps[idx] = s; Pn[idx] = mn; Px[idx] = mx;
    }
}

// ---------------- conv3: i8 MFMA, A=acts (M=128 j), B=weights (N=128 co), K=256 single stage ----------------
// float4 NCHW stores to d_out + per-block partial stats.
__global__ __launch_bounds__(256, 2) void k_conv3(const signed char* __restrict__ Wts,
                                                  const signed char* __restrict__ Zc,
                                                  const float* __restrict__ R, const float* __restrict__ Cj,
                                                  const float* __restrict__ pw, const float* __restrict__ pz,
                                                  float* __restrict__ out,
                                                  float* __restrict__ Ps, float* __restrict__ Pn,
                                                  float* __restrict__ Px) {
    __shared__ __align__(16) signed char As[32768];   // acts: 128 j x 256B
    __shared__ __align__(16) signed char Bs[32768];   // wts : 128 co x 256B
    __shared__ float Lst[2][128][3];
    int tid = threadIdx.x, lane = tid & 63, wave = tid >> 6;
    int wm = wave >> 1, wn = wave & 1;
    int jb = blockIdx.x * 128, cob = blockIdx.y * 128;
    int sr = tid >> 4, spos = tid & 15;
#pragma unroll
    for (int p = 0; p < 8; p++) {
        int row = p * 16 + sr;
        int cg = spos ^ (row & 7);
        glds16(Zc + (size_t)(jb + row) * 256 + cg * 16, &As[p * 4096 + tid * 16]);
    }
#pragma unroll
    for (int p = 0; p < 8; p++) {
        int row = p * 16 + sr;
        int cg = spos ^ (row & 7);
        glds16(Wts + (size_t)(cob + row) * 256 + cg * 16, &Bs[p * 4096 + tid * 16]);
    }
    __syncthreads();

    int4v acc[4][4];
#pragma unroll
    for (int mi = 0; mi < 4; mi++)
#pragma unroll
        for (int ni = 0; ni < 4; ni++) acc[mi][ni] = (int4v)0;

    int l15 = lane & 15, kq = lane >> 4, sw = l15 & 7;
#pragma unroll
    for (int kc = 0; kc < 4; kc++) {
        int col = ((kc * 4 + kq) ^ sw) << 4;
        int4v a[4], bb[4];
#pragma unroll
        for (int mi = 0; mi < 4; mi++)
            a[mi] = *(const int4v*)&As[(wm * 64 + mi * 16 + l15) * 256 + col];
#pragma unroll
        for (int ni = 0; ni < 4; ni++)
            bb[ni] = *(const int4v*)&Bs[(wn * 64 + ni * 16 + l15) * 256 + col];
#pragma unroll
        for (int mi = 0; mi < 4; mi++)
#pragma unroll
            for (int ni = 0; ni < 4; ni++)
                acc[mi][ni] = __builtin_amdgcn_mfma_i32_16x16x64_i8(a[mi], bb[ni], acc[mi][ni], 0, 0, 0);
    }

    float aw = pw[1], bw = pw[0] + 128.f * pw[1];
    float az = pz[1], bz = pz[0] + 128.f * pz[1];
    float caa = aw * az, cR = aw * bz, cC = bw * az, cK = bw * bz;
    int coA[4]; float rA[4];
#pragma unroll
    for (int ni = 0; ni < 4; ni++) {
        coA[ni] = cob + wn * 64 + ni * 16 + l15;
        rA[ni] = R[coA[ni]];
    }
    float ps[4], pmn[4], pmx[4];
#pragma unroll
    for (int ni = 0; ni < 4; ni++) { ps[ni] = 0.f; pmn[ni] = INFINITY; pmx[ni] = -INFINITY; }
#pragma unroll
    for (int mi = 0; mi < 4; mi++) {
        int j0 = jb + wm * 64 + mi * 16 + kq * 4;
        int n = j0 / 196, hh = j0 - n * 196;
        float4 cj = *(const float4*)&Cj[j0];
#pragma unroll
        for (int ni = 0; ni < 4; ni++) {
            float base = cR * rA[ni] + cK * 256.f;
            float4 v;
            v.x = caa * (float)acc[mi][ni][0] + base + cC * cj.x;
            v.y = caa * (float)acc[mi][ni][1] + base + cC * cj.y;
            v.z = caa * (float)acc[mi][ni][2] + base + cC * cj.z;
            v.w = caa * (float)acc[mi][ni][3] + base + cC * cj.w;
            *(float4*)&out[((size_t)n * 1024 + coA[ni]) * 196 + hh] = v;
            ps[ni] += v.x + v.y + v.z + v.w;
            pmn[ni] = fminf(pmn[ni], fminf(fminf(v.x, v.y), fminf(v.z, v.w)));
            pmx[ni] = fmaxf(pmx[ni], fmaxf(fmaxf(v.x, v.y), fmaxf(v.z, v.w)));
        }
    }
#pragma unroll
    for (int ni = 0; ni < 4; ni++) {
        float s = ps[ni], mn = pmn[ni], mx = pmx[ni];
        s += __shfl_xor(s, 16, 64); s += __shfl_xor(s, 32, 64);
        mn = fminf(mn, __shfl_xor(mn, 16, 64)); mn = fminf(mn, __shfl_xor(mn, 32, 64));
        mx = fmaxf(mx, __shfl_xor(mx, 16, 64)); mx = fmaxf(mx, __shfl_xor(mx, 32, 64));
        if (kq == 0) {
            int cl = wn * 64 + ni * 16 + l15;
            Lst[wm][cl][0] = s; Lst[wm][cl][1] = mn; Lst[wm][cl][2] = mx;
        }
    }
    __syncthreads();
    if (tid < 128) {
        float s  = Lst[0][tid][0] + Lst[1][tid][0];
        float mn = fminf(Lst[0][tid][1], Lst[1][tid][1]);
        float mx = fmaxf(Lst[0][tid][2], Lst[1][tid][2]);
        int idx = blockIdx.x * 1024 + cob + tid;
        Ps[idx] = s; Pn[idx] = mn; Px[idx] = mx;
    }
}

// ---------------- reduce per-block partial stats over 98 jb-tiles ----------------
__global__ __launch_bounds__(256) void k_redstats(const float* __restrict__ Ps, const float* __restrict__ Pn,
                                                  const float* __restrict__ Px, int C,
                                                  float* __restrict__ sum_o, float* __restrict__ mn_o,
                                                  float* __restrict__ mx_o) {
    __shared__ float Ls[4][64][3];
    int t = threadIdx.x, cl = t & 63, sl = t >> 6;
    int co = blockIdx.x * 64 + cl;
    float s = 0.f, mn = INFINITY, mx = -INFINITY;
    for (int b = sl; b < 98; b += 4) {
        s += Ps[b * C + co];
        mn = fminf(mn, Pn[b * C + co]);
        mx = fmaxf(mx, Px[b * C + co]);
    }
    Ls[sl][cl][0] = s; Ls[sl][cl][1] = mn; Ls[sl][cl][2] = mx;
    __syncthreads();
    if (t < 64) {
        s = Ls[0][t][0] + Ls[1][t][0] + Ls[2][t][0] + Ls[3][t][0];
        mn = fminf(fminf(Ls[0][t][1], Ls[1][t][1]), fminf(Ls[2][t][1], Ls[3][t][1]));
        mx = fmaxf(fmaxf(Ls[0][t][2], Ls[1][t][2]), fmaxf(Ls[2][t][2], Ls[3][t][2]));
        int co2 = blockIdx.x * 64 + t;
        sum_o[co2] = s; mn_o[co2] = mn; mx_o[co2] = mx;
    }
}

// ---------------- finalize range_norm ----------------
__global__ __launch_bounds__(256) void k_finnorm(int C, const float* __restrict__ gamma, const float* __restrict__ beta,
                                                 const float* __restrict__ sum_i, const float* __restrict__ mn_i,
                                                 const float* __restrict__ mx_i, float* mean_o, float* sg_o,
                                                 float* qp, float scale_fix) {
    int tid = threadIdx.x;
    int lane = tid & 63, w = tid >> 6;
    __shared__ float sa[4], sb[4];
    float gmn = INFINITY, gmx = -INFINITY;
    for (int c = tid; c < C; c += 256) { float g = gamma[c]; gmn = fminf(gmn, g); gmx = fmaxf(gmx, g); }
    for (int o = 32; o; o >>= 1) { gmn = fminf(gmn, __shfl_down(gmn, o, 64)); gmx = fmaxf(gmx, __shfl_down(gmx, o, 64)); }
    if (lane == 0) { sa[w] = gmn; sb[w] = gmx; }
    __syncthreads();
    gmn = fminf(fminf(sa[0], sa[1]), fminf(sa[2], sa[3]));
    gmx = fmaxf(fmaxf(sb[0], sb[1]), fmaxf(sb[2], sb[3]));
    float gsc = fmaxf((gmx - gmn) / 255.0f, 1e-8f);
    __syncthreads();
    float qmn = INFINITY, qmx = -INFINITY;
    for (int c = tid; c < C; c += 256) {
        float mean = sum_i[c] / 12544.0f;
        float cmn = mn_i[c], cmx = mx_i[c];
        float rng = cmx - cmn;
        float qg = fqv(gamma[c], gmn, gsc);
        float s = qg / (rng * scale_fix + 1e-5f);
        mean_o[c] = mean; sg_o[c] = s;
        float b = beta[c];
        float lo = (cmn - mean) * s + b;
        float hi = (cmx - mean) * s + b;
        qmn = fminf(qmn, fminf(lo, hi));
        qmx = fmaxf(qmx, fmaxf(lo, hi));
    }
    for (int o = 32; o; o >>= 1) { qmn = fminf(qmn, __shfl_down(qmn, o, 64)); qmx = fmaxf(qmx, __shfl_down(qmx, o, 64)); }
    if (lane == 0) { sa[w] = qmn; sb[w] = qmx; }
    __syncthreads();
    if (tid == 0) {
        qmn = fminf(fminf(sa[0], sa[1]), fminf(sa[2], sa[3]));
        qmx = fmaxf(fmaxf(sb[0], sb[1]), fmaxf(sb[2], sb[3]));
        qp[0] = qmn;
        qp[1] = fmaxf((qmx - qmn) / 255.0f, 1e-8f);
    }
}

// ---------------- final: out = fq(x) + fq(norm3(out3)) in place ----------------
__global__ __launch_bounds__(256) void k_final(const float* __restrict__ x, float* __restrict__ out,
                                               const float* __restrict__ mean, const float* __restrict__ sg,
                                               const float* __restrict__ beta, const float* __restrict__ sf,
                                               const float* __restrict__ qp) {
    float xmn = sf[8], xsc = sf[9];
    float qmn = qp[0], qsc = qp[1];
    const float4* xp = (const float4*)x;
    float4* yp = (float4*)out;
    int n4 = 12845056 / 4;
    int i = blockIdx.x * blockDim.x + threadIdx.x;
    int str = gridDim.x * blockDim.x;
    for (; i < n4; i += str) {
        int e = i * 4;
        int c = (e / 196) & 1023;
        float m = mean[c], s = sg[c], b = beta[c];
        float4 xv = xp[i], ov = yp[i], r;
        r.x = fqv(xv.x, xmn, xsc) + fqv((ov.x - m) * s + b, qmn, qsc);
        r.y = fqv(xv.y, xmn, xsc) + fqv((ov.y - m) * s + b, qmn, qsc);
        r.z = fqv(xv.z, xmn, xsc) + fqv((ov.z - m) * s + b, qmn, qsc);
        r.w = fqv(xv.w, xmn, xsc) + fqv((ov.w - m) * s + b, qmn, qsc);
        yp[i] = r;
    }
}

extern "C" void kernel_launch(void* const* d_in, const int* in_sizes, int n_in,
                              void* d_out, int out_size, void* d_ws, size_t ws_size,
                              hipStream_t stream) {
    const float* x  = (const float*)d_in[0];
    const float* w1 = (const float*)d_in[1];
    const float* g1 = (const float*)d_in[2];
    const float* b1 = (const float*)d_in[3];
    const float* w2 = (const float*)d_in[4];
    const float* g2 = (const float*)d_in[5];
    const float* b2 = (const float*)d_in[6];
    const float* w3 = (const float*)d_in[7];
    const float* g3 = (const float*)d_in[8];
    const float* b3 = (const float*)d_in[9];
    float* out = (float*)d_out;

    float* W = (float*)d_ws;
    float* OUT = W + OF_OUT;
    signed char* xc  = (signed char*)(W + OF_XC);
    signed char* z1p = (signed char*)(W + OF_Z1P);
    signed char* z2c = (signed char*)(W + OF_Z2C);
    signed char* wq1 = (signed char*)(W + OF_WQ1);
    signed char* wq2 = (signed char*)(W + OF_WQ2);
    signed char* wq3 = (signed char*)(W + OF_WQ3);
    float* R1 = W + OF_R1; float* R2 = W + OF_R2; float* R3 = W + OF_R3;
    float* T2 = W + OF_T2;
    float* CX = W + OF_CX; float* U2 = W + OF_U2; float* V2 = W + OF_V2; float* CZ = W + OF_CZ;
    float* P1s = W + OF_P1, *P1n = P1s + 25088, *P1x = P1s + 50176;
    float* P2s = W + OF_P2, *P2n = P2s + 25088, *P2x = P2s + 50176;
    float* P3s = W + OF_P3, *P3n = P3s + 100352, *P3x = P3s + 200704;
    float* Pmm = W + OF_PMM;
    float* RS = W + OF_RS;
    float* sum1 = RS, *mn1 = RS + 256, *mx1 = RS + 512;
    float* sum2 = RS + 768, *mn2 = RS + 1024, *mx2 = RS + 1280;
    float* sum3 = RS + 1536, *mn3 = RS + 2560, *mx3 = RS + 3584;
    float* S = W + OF_ST;
    float* MS = W + OF_MS;
    float* mean1 = MS, *sg1 = MS + 256, *mean2 = MS + 512, *sg2 = MS + 768, *mean3 = MS + 1024, *sg3 = MS + 2048;

    const float scale_fix =
        (float)((0.5 * 0.35) * (1.0 + sqrt(M_PI * log(4.0))) / sqrt(2.0 * log(12544.0)));

    // zero scratch regions that need it
    hipMemsetAsync(CX, 0, 12544 * 4, stream);
    hipMemsetAsync(U2, 0, 16384 * 4, stream);
    hipMemsetAsync(z1p, 0, 4194304, stream);

    // fq params for x, w1, w2, w3 (two-phase, no atomics)
    k_minmax_all<<<1280, 256, 0, stream>>>((const float4*)x, (const float4*)w1,
                                           (const float4*)w2, (const float4*)w3, Pmm);
    k_fqparams2<<<1, 256, 0, stream>>>(Pmm, S);

    // weight codes + reductions (single launch)
    k_wcode_all<<<1536, 256, 0, stream>>>(w1, w2, w3, S, wq1, wq2, wq3, R1, R2, R3, T2);

    // x -> NHWC i8 codes + CX
    k_code0<<<dim3(7, 4, 64), 256, 0, stream>>>(x, xc, S + 8, CX);

    // conv1 -> OUT NHWC + stage1 partials
    k_conv12<0><<<dim3(98, 4), 256, 0, stream>>>(xc, wq1, R1, nullptr, CX, S + 11, S + 8, OUT, 1024,
                                                 P1s, P1n, P1x);
    k_redstats<<<4, 256, 0, stream>>>(P1s, P1n, P1x, 256, sum1, mn1, mx1);
    k_finnorm<<<1, 256, 0, stream>>>(256, g1, b1, sum1, mn1, mx1, mean1, sg1, S + 20, scale_fix);
    k_codeE<1><<<784, 256, 0, stream>>>(OUT, z1p, mean1, sg1, b1, S + 20, U2);
    k_v2<<<49, 256, 0, stream>>>(U2, V2);

    // conv2 -> OUT NHWC + stage2 partials
    k_conv12<1><<<dim3(98, 4), 256, 0, stream>>>(z1p, wq2, R2, T2, V2, S + 14, S + 20, OUT, 2304,
                                                 P2s, P2n, P2x);
    k_redstats<<<4, 256, 0, stream>>>(P2s, P2n, P2x, 256, sum2, mn2, mx2);
    k_finnorm<<<1, 256, 0, stream>>>(256, g2, b2, sum2, mn2, mx2, mean2, sg2, S + 23, scale_fix);
    k_codeE<0><<<784, 256, 0, stream>>>(OUT, z2c, mean2, sg2, b2, S + 23, CZ);

    // conv3 -> d_out NCHW (float4 stores) + stage3 partials
    k_conv3<<<dim3(98, 8), 256, 0, stream>>>(wq3, z2c, R3, CZ, S + 17, S + 23, out, P3s, P3n, P3x);
    k_redstats<<<16, 256, 0, stream>>>(P3s, P3n, P3x, 1024, sum3, mn3, mx3);
    k_finnorm<<<1, 256, 0, stream>>>(1024, g3, b3, sum3, mn3, mx3, mean3, sg3, S + 26, scale_fix);
    k_final<<<2048, 256, 0, stream>>>(x, out, mean3, sg3, b3, S, S + 26);
}